// Round 3
// baseline (7818.136 us; speedup 1.0000x reference)
//
#include <hip/hip_runtime.h>

// ---------------------------------------------------------------------------
// ComNet: R=16 runs x T=512 steps x 32 agents, sequential agent scan.
//   k0: transpose W1[:, :93] -> w1T
//   k1: pre1[rti][h] = b1[h] + xs(93) . W1xs  (parallel, bulk of FLOPs)
//   k2: wave-synchronous sequential kernel, 16 blocks x 1 wave.
// R6: fp16 h1 LDS + v_dot2 + clampless tanh + off-chain o0/o1: 6827->5520us.
// R7: pre1 t-rows staged through a double-buffered LDS ring. PROVEN 5569us.
// R8/R8b: in-register all-gather of h1 (DPP doubling tree + permlane swaps)
//   replacing the on-chain LDS round trip. Both FAILED with IDENTICAL absmax
//   0.345 -> pack & pair-order exonerated; some primitive deviates from my
//   model in a probe-invisible way.
// R9: SELF-VERIFYING HYBRID. At kernel start, run the gather tree on a known
//   test vector (h1[l]=l+1, exact in f16) and check all 32 gathered dwords
//   in every lane (__all) -> wave-uniform gok. template<bool GATHER> core:
//   gok ? register-gather step : proven R7 LDS-broadcast step. Passes either
//   way; dur_us reports which path validated on-device.
// ---------------------------------------------------------------------------

#define R_RUNS 16
#define T_STEPS 512
#define NA 32
#define HID 64
#define XS 93                       // (NA-1)*3
#define DIN 124
#define STEPS_PER_RUN (T_STEPS * NA)        // 16384
#define RTI_TOT (R_RUNS * STEPS_PER_RUN)    // 262144

#define PRE1_OFF 65536
#define WS_NEEDED ((size_t)PRE1_OFF + (size_t)RTI_TOT * HID * 4 + 4096)

typedef _Float16 half2_t __attribute__((ext_vector_type(2)));
typedef unsigned int uint2v __attribute__((ext_vector_type(2)));

#if defined(__has_builtin)
#if __has_builtin(__builtin_amdgcn_permlane16_swap) && __has_builtin(__builtin_amdgcn_permlane32_swap)
#define HAVE_PLSWAP 1
#endif
#endif
#ifndef HAVE_PLSWAP
#define HAVE_PLSWAP 0
#endif

__device__ __forceinline__ float fast_tanh(float x) {
  // tanh(x) = 1 - 2/(e^{2x}+1); exp(+inf)->rcp(inf)=0 -> 1; exp(-inf)=0 -> -1.
  float e = __expf(2.f * x);
  return fmaf(-2.f, __builtin_amdgcn_rcpf(e + 1.f), 1.f);
}

__device__ __forceinline__ float dot2h(half2_t a, half2_t b, float c) {
#if __has_builtin(__builtin_amdgcn_fdot2)
  return __builtin_amdgcn_fdot2(a, b, c, false);
#else
  return fmaf((float)a.x, (float)b.x, fmaf((float)a.y, (float)b.y, c));
#endif
}

__device__ __forceinline__ half2_t bch(unsigned u) {
  return __builtin_bit_cast(half2_t, u);
}

#define DPP_ADD(x, ctrl, rmask) \
  (x) += __int_as_float(__builtin_amdgcn_update_dpp(0, __float_as_int(x), (ctrl), (rmask), 0xf, true))

__device__ __forceinline__ float wave64_sum_bcast(float x) {
  DPP_ADD(x, 0x111, 0xf);
  DPP_ADD(x, 0x112, 0xf);
  DPP_ADD(x, 0x114, 0xf);
  DPP_ADD(x, 0x118, 0xf);
  DPP_ADD(x, 0x142, 0xa);
  DPP_ADD(x, 0x143, 0xc);
  return __int_as_float(__builtin_amdgcn_readlane(__float_as_int(x), 63));
}

// two interleaved sums, totals left in lane 63 (consumer is lane 63)
__device__ __forceinline__ void wave64_sum2_l63(float& x0, float& x1) {
#define ST2(ctrl, rmask) DPP_ADD(x0, ctrl, rmask); DPP_ADD(x1, ctrl, rmask)
  ST2(0x111, 0xf);
  ST2(0x112, 0xf);
  ST2(0x114, 0xf);
  ST2(0x118, 0xf);
  ST2(0x142, 0xa);
  ST2(0x143, 0xc);
#undef ST2
}

// dpp-mov (all rows/banks, bound_ctrl on; all source lanes valid for our ctrls)
template <int CTRL>
__device__ __forceinline__ unsigned dppmov(unsigned v) {
  return (unsigned)__builtin_amdgcn_update_dpp(0, (int)v, CTRL, 0xf, 0xf, true);
}

#if HAVE_PLSWAP
__device__ __forceinline__ uint2v pl16swap(unsigned a) {
  return __builtin_amdgcn_permlane16_swap(a, a, false, false);
}
__device__ __forceinline__ uint2v pl32swap(unsigned a) {
  return __builtin_amdgcn_permlane32_swap(a, a, false, false);
}

// The gather tree: input IN = zero-extended f16 of this lane's h1.
// Output: P##fd0..P##fd15 (uint2v); intended: P##fdJ[0] = packed h1 dword J,
// P##fdJ[1] = packed h1 dword 16+J (absolute order, wave-uniform).
// Uses odd1/s2/s4/s8 bools from enclosing scope.
#define GATHER_TREE(IN, P)                                                   \
  const unsigned P##tA  = dppmov<0xB1>(IN);   /* quad_perm[1,0,3,2]: ^1 */   \
  const unsigned P##plo = odd1 ? P##tA : (IN);                               \
  const unsigned P##phi = odd1 ? (IN) : P##tA;                               \
  const unsigned P##D0  = P##plo | (P##phi << 16);  /* dword p = h>>1 */     \
  const unsigned P##tB  = dppmov<0x4E>(P##D0); /* quad_perm[2,3,0,1]: ^2 */  \
  const unsigned P##E0  = s2 ? P##tB : P##D0;  /* dword 2q   */              \
  const unsigned P##E1  = s2 ? P##D0 : P##tB;  /* dword 2q+1 */              \
  const unsigned P##tC0 = dppmov<0x141>(P##E0); /* row_half_mirror: ^7 */    \
  const unsigned P##tC1 = dppmov<0x141>(P##E1);                              \
  const unsigned P##F0  = s4 ? P##tC0 : P##E0; /* dwords 4Q..4Q+3 */         \
  const unsigned P##F1  = s4 ? P##tC1 : P##E1;                               \
  const unsigned P##F2  = s4 ? P##E0 : P##tC0;                               \
  const unsigned P##F3  = s4 ? P##E1 : P##tC1;                               \
  const unsigned P##tD0 = dppmov<0x140>(P##F0); /* row_mirror: ^15 */        \
  const unsigned P##tD1 = dppmov<0x140>(P##F1);                              \
  const unsigned P##tD2 = dppmov<0x140>(P##F2);                              \
  const unsigned P##tD3 = dppmov<0x140>(P##F3);                              \
  const unsigned P##G0 = s8 ? P##tD0 : P##F0;  /* dwords 8R..8R+7 */         \
  const unsigned P##G1 = s8 ? P##tD1 : P##F1;                                \
  const unsigned P##G2 = s8 ? P##tD2 : P##F2;                                \
  const unsigned P##G3 = s8 ? P##tD3 : P##F3;                                \
  const unsigned P##G4 = s8 ? P##F0 : P##tD0;                                \
  const unsigned P##G5 = s8 ? P##F1 : P##tD1;                                \
  const unsigned P##G6 = s8 ? P##F2 : P##tD2;                                \
  const unsigned P##G7 = s8 ? P##F3 : P##tD3;                                \
  const uint2v P##e0 = pl16swap(P##G0);                                      \
  const uint2v P##e1 = pl16swap(P##G1);                                      \
  const uint2v P##e2 = pl16swap(P##G2);                                      \
  const uint2v P##e3 = pl16swap(P##G3);                                      \
  const uint2v P##e4 = pl16swap(P##G4);                                      \
  const uint2v P##e5 = pl16swap(P##G5);                                      \
  const uint2v P##e6 = pl16swap(P##G6);                                      \
  const uint2v P##e7 = pl16swap(P##G7);                                      \
  const uint2v P##fd0 = pl32swap(P##e0[0]);                                  \
  const uint2v P##fd1 = pl32swap(P##e1[0]);                                  \
  const uint2v P##fd2 = pl32swap(P##e2[0]);                                  \
  const uint2v P##fd3 = pl32swap(P##e3[0]);                                  \
  const uint2v P##fd4 = pl32swap(P##e4[0]);                                  \
  const uint2v P##fd5 = pl32swap(P##e5[0]);                                  \
  const uint2v P##fd6 = pl32swap(P##e6[0]);                                  \
  const uint2v P##fd7 = pl32swap(P##e7[0]);                                  \
  const uint2v P##fd8  = pl32swap(P##e0[1]);                                 \
  const uint2v P##fd9  = pl32swap(P##e1[1]);                                 \
  const uint2v P##fd10 = pl32swap(P##e2[1]);                                 \
  const uint2v P##fd11 = pl32swap(P##e3[1]);                                 \
  const uint2v P##fd12 = pl32swap(P##e4[1]);                                 \
  const uint2v P##fd13 = pl32swap(P##e5[1]);                                 \
  const uint2v P##fd14 = pl32swap(P##e6[1]);                                 \
  const uint2v P##fd15 = pl32swap(P##e7[1])

// expected packed dword d of the test vector h1[l] = l+1
__device__ __forceinline__ unsigned expd(int d) {
  unsigned lo = (unsigned)__builtin_bit_cast(unsigned short, (_Float16)(float)(2 * d + 1));
  unsigned hi = (unsigned)__builtin_bit_cast(unsigned short, (_Float16)(float)(2 * d + 2));
  return lo | (hi << 16);
}
#endif

// ---------------- k0: transpose W1 xs-part ----------------
__global__ void transpose_w1(const float* __restrict__ w1, float* __restrict__ w1T) {
  int idx = blockIdx.x * blockDim.x + threadIdx.x;  // idx = k*64 + h
  if (idx < XS * HID) {
    int k = idx / HID, h = idx % HID;
    w1T[idx] = w1[h * DIN + k];
  }
}

// ---------------- k1: pre1 = b1 + xs @ W1xs^T ----------------
__global__ __launch_bounds__(256) void pre1_kernel(
    const float* __restrict__ runs, const float* __restrict__ w1T,
    const float* __restrict__ b1, float* __restrict__ pre1) {
  const int wid = (blockIdx.x * 256 + threadIdx.x) >> 6;  // rti, one wave each
  const int lane = threadIdx.x & 63;
  const float* xs = runs + (size_t)wid * XS;   // wave-uniform: broadcast loads
  float a0 = b1[lane], a1 = 0.f, a2 = 0.f;
#pragma unroll 4
  for (int k = 0; k < 31; ++k) {
    a0 = fmaf(xs[3 * k],     w1T[(3 * k) * HID + lane],     a0);
    a1 = fmaf(xs[3 * k + 1], w1T[(3 * k + 1) * HID + lane], a1);
    a2 = fmaf(xs[3 * k + 2], w1T[(3 * k + 2) * HID + lane], a2);
  }
  pre1[(size_t)wid * HID + lane] = (a0 + a1) + a2;
}

// ---------------- k2 core: the t/i loops, gather vs LDS broadcast ----------
// A[h][j] = w1[h][93+j] (j<=30, pad 0), B[h][j] = w1[h][92+j] (j>=1, pad 0).
// h1pre = pre1 + FB + Q - S; FB refreshed per t from commL; S snapshot-based;
// Q += A[h][i]*c_new.
template <bool GATHER>
__device__ __forceinline__ void seq_core(
    const int h, const int r, const int hb,
    const float* __restrict__ w2, const float* __restrict__ b2,
    const float* __restrict__ w3, const float* __restrict__ b3,
    const float* __restrict__ comm_init, const float* __restrict__ pre1,
    float* __restrict__ out,
    float* Asl, float* Bsl, float* commL, _Float16* h1s16,
    float2* oL, float (*pbuf)[2048 + 64]) {
  const bool odd1 = (h & 1) != 0;
  const bool s2 = (h & 2) != 0, s4 = (h & 4) != 0, s8 = (h & 8) != 0;
  (void)odd1; (void)s2; (void)s4; (void)s8;

  // W2 row h -> 32 NAMED half2 (no array -> no SROA demotion).
  const float4* w2v = (const float4*)(w2 + h * HID);
  const float4 r0 = w2v[0],  r1 = w2v[1],  r2 = w2v[2],  r3 = w2v[3];
  const float4 r4 = w2v[4],  r5 = w2v[5],  r6 = w2v[6],  r7 = w2v[7];
  const float4 r8 = w2v[8],  r9 = w2v[9],  r10 = w2v[10], r11 = w2v[11];
  const float4 r12 = w2v[12], r13 = w2v[13], r14 = w2v[14], r15 = w2v[15];
#define PK2(n, f4) \
  const half2_t n##a = {(_Float16)(f4).x, (_Float16)(f4).y}; \
  const half2_t n##b = {(_Float16)(f4).z, (_Float16)(f4).w}
  PK2(q0, r0);  PK2(q1, r1);  PK2(q2, r2);  PK2(q3, r3);
  PK2(q4, r4);  PK2(q5, r5);  PK2(q6, r6);  PK2(q7, r7);
  PK2(q8, r8);  PK2(q9, r9);  PK2(q10, r10); PK2(q11, r11);
  PK2(q12, r12); PK2(q13, r13); PK2(q14, r14); PK2(q15, r15);
#undef PK2

  const float b2h = b2[h];
  const float w30h = w3[h], w31h = w3[HID + h], w32h = w3[2 * HID + h];
  const float b30 = b3[0], b31 = b3[1], b32 = b3[2];

  float commR = (h < NA) ? comm_init[r * NA + h] : 0.f;  // lane j holds comm[j]
  if (h < NA) commL[h] = commR;                          // mirror for FB refresh

  const float* prow = pre1 + (size_t)r * STEPS_PER_RUN * HID;  // + t*2048 floats

  // prime rows 0 and 1 into the LDS ring (one-time)
  {
    const float4* s0 = (const float4*)prow;
    const float4* s1 = (const float4*)(prow + 2048);
    float4* d0 = (float4*)&pbuf[0][0];
    float4* d1 = (float4*)&pbuf[1][0];
#pragma unroll
    for (int j = 0; j < 8; ++j) d0[j * 64 + h] = s0[j * 64 + h];
#pragma unroll
    for (int j = 0; j < 8; ++j) d1[j * 64 + h] = s1[j * 64 + h];
  }

  float* outw = out + (size_t)r * STEPS_PER_RUN * 2;

  for (int t = 0; t < T_STEPS; ++t) {
    float* pb = pbuf[t & 1];
    // prefetch row t+2 into 8 named float4 regs; retires during the long body;
    // consumed by the ds_writes at the end of this t. Fully off-chain.
    int tk = (t + 2 <= T_STEPS - 1) ? t + 2 : T_STEPS - 1;
    const float4* gsrc = (const float4*)(prow + (size_t)tk * 2048);
    float4 g0 = gsrc[0 * 64 + h], g1 = gsrc[1 * 64 + h];
    float4 g2 = gsrc[2 * 64 + h], g3 = gsrc[3 * 64 + h];
    float4 g4 = gsrc[4 * 64 + h], g5 = gsrc[5 * 64 + h];
    float4 g6 = gsrc[6 * 64 + h], g7 = gsrc[7 * 64 + h];

    // FB refresh (amortized over 32 steps); commL was finalized at end of t-1.
    const float4* cv4 = (const float4*)commL;
    float f0 = 0.f, f1 = 0.f, f2 = 0.f, f3 = 0.f;
#pragma unroll
    for (int q = 0; q < 8; ++q) {
      float4 c = cv4[q];
      f0 = fmaf(Bsl[hb + 4 * q + 0], c.x, f0);
      f1 = fmaf(Bsl[hb + 4 * q + 1], c.y, f1);
      f2 = fmaf(Bsl[hb + 4 * q + 2], c.z, f2);
      f3 = fmaf(Bsl[hb + 4 * q + 3], c.w, f3);
    }
    const float FB = (f0 + f1) + (f2 + f3);
    const float c0s = commR;           // t-start snapshot: old_i source, off-chain
    float Q = 0.f, S = 0.f;
    float pf_cur = pb[h];              // step-0 value (hidden under FB refresh)
    float A_cur = Asl[hb], B_cur = Bsl[hb];

#pragma unroll 4
    for (int i = 0; i < NA; ++i) {
      // 1-ahead pipelined LDS reads (i=31 hits the pad slot / entry 32 -> unused)
      float pf_n = pb[(i + 1) * 64 + h];
      float A_n = Asl[hb + i + 1];
      float B_n = Bsl[hb + i + 1];
      float old_i = __int_as_float(__builtin_amdgcn_readlane(__float_as_int(c0s), i));
      S = fmaf(B_cur, old_i, S);       // off the c_new chain (snapshot-based)
      float h1 = fast_tanh(pf_cur + (FB - S) + Q);   // chain: Q enters here
      float a0 = b2h, a1 = 0.f, a2 = 0.f, a3 = 0.f;
      if constexpr (GATHER) {
#if HAVE_PLSWAP
        // in-register all-gather, validated by the kernel-entry self-test
        unsigned c16 = (unsigned)__builtin_bit_cast(unsigned short, (_Float16)h1);
        GATHER_TREE(c16, S_);
        // slot s <-> dword s; weight half2 q_{s>>1}{s&1?b:a}; chain s&3.
        a0 = dot2h(q0a,  bch(S_fd0[0]),  a0);
        a1 = dot2h(q0b,  bch(S_fd1[0]),  a1);
        a2 = dot2h(q1a,  bch(S_fd2[0]),  a2);
        a3 = dot2h(q1b,  bch(S_fd3[0]),  a3);
        a0 = dot2h(q2a,  bch(S_fd4[0]),  a0);
        a1 = dot2h(q2b,  bch(S_fd5[0]),  a1);
        a2 = dot2h(q3a,  bch(S_fd6[0]),  a2);
        a3 = dot2h(q3b,  bch(S_fd7[0]),  a3);
        a0 = dot2h(q4a,  bch(S_fd8[0]),  a0);
        a1 = dot2h(q4b,  bch(S_fd9[0]),  a1);
        a2 = dot2h(q5a,  bch(S_fd10[0]), a2);
        a3 = dot2h(q5b,  bch(S_fd11[0]), a3);
        a0 = dot2h(q6a,  bch(S_fd12[0]), a0);
        a1 = dot2h(q6b,  bch(S_fd13[0]), a1);
        a2 = dot2h(q7a,  bch(S_fd14[0]), a2);
        a3 = dot2h(q7b,  bch(S_fd15[0]), a3);
        a0 = dot2h(q8a,  bch(S_fd0[1]),  a0);
        a1 = dot2h(q8b,  bch(S_fd1[1]),  a1);
        a2 = dot2h(q9a,  bch(S_fd2[1]),  a2);
        a3 = dot2h(q9b,  bch(S_fd3[1]),  a3);
        a0 = dot2h(q10a, bch(S_fd4[1]),  a0);
        a1 = dot2h(q10b, bch(S_fd5[1]),  a1);
        a2 = dot2h(q11a, bch(S_fd6[1]),  a2);
        a3 = dot2h(q11b, bch(S_fd7[1]),  a3);
        a0 = dot2h(q12a, bch(S_fd8[1]),  a0);
        a1 = dot2h(q12b, bch(S_fd9[1]),  a1);
        a2 = dot2h(q13a, bch(S_fd10[1]), a2);
        a3 = dot2h(q13b, bch(S_fd11[1]), a3);
        a0 = dot2h(q14a, bch(S_fd12[1]), a0);
        a1 = dot2h(q14b, bch(S_fd13[1]), a1);
        a2 = dot2h(q15a, bch(S_fd14[1]), a2);
        a3 = dot2h(q15b, bch(S_fd15[1]), a3);
#endif
      } else {
        // proven R7 path: LDS round-trip broadcast
        h1s16[h] = (_Float16)h1;
        const uint4* hv = (const uint4*)h1s16;   // broadcast reads, 8 b128
        uint4 X0 = hv[0], X1 = hv[1], X2 = hv[2], X3 = hv[3];
        uint4 X4 = hv[4], X5 = hv[5], X6 = hv[6], X7 = hv[7];
#define DOTB(Xq, qe, qo) \
        a0 = dot2h(qe##a, bch(Xq.x), a0); a1 = dot2h(qe##b, bch(Xq.y), a1); \
        a2 = dot2h(qo##a, bch(Xq.z), a2); a3 = dot2h(qo##b, bch(Xq.w), a3)
        DOTB(X0, q0, q1);   DOTB(X1, q2, q3);
        DOTB(X2, q4, q5);   DOTB(X3, q6, q7);
        DOTB(X4, q8, q9);   DOTB(X5, q10, q11);
        DOTB(X6, q12, q13); DOTB(X7, q14, q15);
#undef DOTB
      }
      float h2 = fast_tanh((a0 + a1) + (a2 + a3));
      // --- on-chain: c_new reduce only (6 dependent DPP + readlane) ---
      float c_new = wave64_sum_bcast(w32h * h2) + b32;
      Q = fmaf(A_cur, c_new, Q);
      commR = (h == i) ? c_new : commR;
      // --- off-chain: o0/o1 reduce sinks into next step's LDS turnaround ---
      float s0v = w30h * h2, s1v = w31h * h2;
      wave64_sum2_l63(s0v, s1v);       // totals in lane 63
      if (h == 63) oL[i] = make_float2(s0v + b30, s1v + b31);
      pf_cur = pf_n; A_cur = A_n; B_cur = B_n;
    }
    if (h < NA) commL[h] = commR;      // mirror refresh, once per t
    // flush this t's 32 x (o0,o1) = 64 floats, one coalesced 256B store.
    outw[h] = ((const float*)oL)[h];
    outw += 2 * NA;
    // stage row t+2 into the buffer just freed (all reads of pb are done;
    // g-regs loaded a full body ago -> no vmcnt stall).
    float4* pd = (float4*)pb;
    pd[0 * 64 + h] = g0; pd[1 * 64 + h] = g1;
    pd[2 * 64 + h] = g2; pd[3 * 64 + h] = g3;
    pd[4 * 64 + h] = g4; pd[5 * 64 + h] = g5;
    pd[6 * 64 + h] = g6; pd[7 * 64 + h] = g7;
  }
}

// ---------------- k2: sequential core (wave-synchronous) ----------------
__global__ __launch_bounds__(64, 1) void seq_kernel(
    const float* __restrict__ w1, const float* __restrict__ w2,
    const float* __restrict__ b2, const float* __restrict__ w3,
    const float* __restrict__ b3, const float* __restrict__ comm_init,
    const float* __restrict__ pre1, float* __restrict__ out) {
  const int h = threadIdx.x;
  const int r = blockIdx.x;
  const int hb = h * 33;              // stride 33: conflict-free, +pad entry 32

  __shared__ float Asl[HID * 33];
  __shared__ float Bsl[HID * 33];
  __shared__ __align__(16) float commL[NA];
  __shared__ __align__(16) _Float16 h1s16[HID];   // fallback h1 broadcast
  __shared__ __align__(16) float2 oL[NA];         // per-t (o0,o1), flushed per t
  __shared__ __align__(16) float pbuf[2][2048 + 64];  // t-row ring + pad read slot

  for (int j = 0; j < 31; ++j) Asl[hb + j] = w1[h * DIN + 93 + j];
  Asl[hb + 31] = 0.f;
  Asl[hb + 32] = 0.f;                 // pad: A_next read at i=31
  Bsl[hb] = 0.f;
  for (int j = 1; j < 32; ++j) Bsl[hb + j] = w1[h * DIN + 92 + j];
  Bsl[hb + 32] = 0.f;                 // pad: B_next read at i=31

  // ---- R9: on-device self-test of the gather tree (full exec, one-time) ----
  bool gok = false;
#if HAVE_PLSWAP
  {
    const bool odd1 = (h & 1) != 0;
    const bool s2 = (h & 2) != 0, s4 = (h & 4) != 0, s8 = (h & 8) != 0;
    unsigned tc = (unsigned)__builtin_bit_cast(unsigned short, (_Float16)(float)(h + 1));
    GATHER_TREE(tc, T_);
    bool ok = true;
    ok &= (T_fd0[0]  == expd(0))  & (T_fd1[0]  == expd(1));
    ok &= (T_fd2[0]  == expd(2))  & (T_fd3[0]  == expd(3));
    ok &= (T_fd4[0]  == expd(4))  & (T_fd5[0]  == expd(5));
    ok &= (T_fd6[0]  == expd(6))  & (T_fd7[0]  == expd(7));
    ok &= (T_fd8[0]  == expd(8))  & (T_fd9[0]  == expd(9));
    ok &= (T_fd10[0] == expd(10)) & (T_fd11[0] == expd(11));
    ok &= (T_fd12[0] == expd(12)) & (T_fd13[0] == expd(13));
    ok &= (T_fd14[0] == expd(14)) & (T_fd15[0] == expd(15));
    ok &= (T_fd0[1]  == expd(16)) & (T_fd1[1]  == expd(17));
    ok &= (T_fd2[1]  == expd(18)) & (T_fd3[1]  == expd(19));
    ok &= (T_fd4[1]  == expd(20)) & (T_fd5[1]  == expd(21));
    ok &= (T_fd6[1]  == expd(22)) & (T_fd7[1]  == expd(23));
    ok &= (T_fd8[1]  == expd(24)) & (T_fd9[1]  == expd(25));
    ok &= (T_fd10[1] == expd(26)) & (T_fd11[1] == expd(27));
    ok &= (T_fd12[1] == expd(28)) & (T_fd13[1] == expd(29));
    ok &= (T_fd14[1] == expd(30)) & (T_fd15[1] == expd(31));
    gok = (__all((int)ok) != 0);
  }
#endif

  if (gok) {
    seq_core<true>(h, r, hb, w2, b2, w3, b3, comm_init, pre1, out,
                   Asl, Bsl, commL, h1s16, oL, pbuf);
  } else {
    seq_core<false>(h, r, hb, w2, b2, w3, b3, comm_init, pre1, out,
                    Asl, Bsl, commL, h1s16, oL, pbuf);
  }
}

// ---------------- fallback: fully fused, zero workspace (unused when ws ok) --
__global__ __launch_bounds__(64, 1) void seq_fused(
    const float* __restrict__ runs, const float* __restrict__ comm_init,
    const float* __restrict__ w1, const float* __restrict__ b1,
    const float* __restrict__ w2, const float* __restrict__ b2,
    const float* __restrict__ w3, const float* __restrict__ b3,
    float* __restrict__ out) {
  const int r = blockIdx.x;
  const int h = threadIdx.x;
  const int hb = h * 33;

  __shared__ float Asl[HID * 33];
  __shared__ float Bsl[HID * 33];
  __shared__ float commL[NA];
  __shared__ __align__(16) float h1s[HID];
  __shared__ float w1xs[XS * HID];
  __shared__ __align__(16) float xsl[96];

  for (int j = 0; j < 31; ++j) Asl[hb + j] = w1[h * DIN + 93 + j];
  Asl[hb + 31] = 0.f;
  Bsl[hb] = 0.f;
  for (int j = 1; j < 32; ++j) Bsl[hb + j] = w1[h * DIN + 92 + j];
  for (int k = 0; k < XS; ++k) w1xs[k * HID + h] = w1[h * DIN + k];

  float w2r[HID];
#pragma unroll
  for (int k = 0; k < HID; ++k) w2r[k] = w2[h * HID + k];
  const float b1h = b1[h];
  const float b2h = b2[h];
  const float w30h = w3[h], w31h = w3[HID + h], w32h = w3[2 * HID + h];
  const float b30 = b3[0], b31 = b3[1], b32 = b3[2];
  if (h < NA) commL[h] = comm_init[r * NA + h];

  const float* xbase = runs + (size_t)r * STEPS_PER_RUN * XS;
  float xa = xbase[h];
  float xb = (h < XS - 64) ? xbase[64 + h] : 0.f;
  float* outp = out + (size_t)r * STEPS_PER_RUN * 2;
  __syncthreads();

  int s = 0;
  for (int t = 0; t < T_STEPS; ++t) {
    float FB = 0.f;
#pragma unroll
    for (int j = 0; j < NA; ++j) FB = fmaf(Bsl[hb + j], commL[j], FB);
    float Q = 0.f, S = 0.f;
    for (int i = 0; i < NA; ++i, ++s) {
      int sn = s + 1; if (sn > STEPS_PER_RUN - 1) sn = STEPS_PER_RUN - 1;
      const float* xn = xbase + (size_t)sn * XS;
      xsl[h] = xa;
      if (h < XS - 64) xsl[64 + h] = xb;
      __syncthreads();
      float xa_n = xn[h];
      float xb_n = (h < XS - 64) ? xn[64 + h] : 0.f;
      float a0 = b1h, a1 = 0.f, a2 = 0.f;
#pragma unroll 4
      for (int k = 0; k < 31; ++k) {
        a0 = fmaf(xsl[3 * k],     w1xs[(3 * k) * HID + h],     a0);
        a1 = fmaf(xsl[3 * k + 1], w1xs[(3 * k + 1) * HID + h], a1);
        a2 = fmaf(xsl[3 * k + 2], w1xs[(3 * k + 2) * HID + h], a2);
      }
      float old_i = commL[i];
      S = fmaf(Bsl[hb + i], old_i, S);
      float h1 = fast_tanh(((a0 + a1) + a2) + FB + Q - S);
      h1s[h] = h1;
      __syncthreads();
      float c0 = b2h, c1 = 0.f, c2 = 0.f, c3 = 0.f;
      const float4* hv4 = (const float4*)h1s;
#pragma unroll
      for (int k4 = 0; k4 < 16; ++k4) {
        float4 hv = hv4[k4];
        c0 = fmaf(w2r[4 * k4 + 0], hv.x, c0);
        c1 = fmaf(w2r[4 * k4 + 1], hv.y, c1);
        c2 = fmaf(w2r[4 * k4 + 2], hv.z, c2);
        c3 = fmaf(w2r[4 * k4 + 3], hv.w, c3);
      }
      float h2 = fast_tanh((c0 + c1) + (c2 + c3));
      float o0 = wave64_sum_bcast(w30h * h2) + b30;
      float o1 = wave64_sum_bcast(w31h * h2) + b31;
      float c_new = wave64_sum_bcast(w32h * h2) + b32;
      if (h == 0) *(float2*)(outp + (size_t)s * 2) = make_float2(o0, o1);
      Q = fmaf(Asl[hb + i], c_new, Q);
      if (h == i) commL[h] = c_new;
      __syncthreads();
      xa = xa_n; xb = xb_n;
    }
  }
}

extern "C" void kernel_launch(void* const* d_in, const int* in_sizes, int n_in,
                              void* d_out, int out_size, void* d_ws, size_t ws_size,
                              hipStream_t stream) {
  const float* runs = (const float*)d_in[0];
  const float* comm_init = (const float*)d_in[1];
  const float* w1 = (const float*)d_in[2];
  const float* b1 = (const float*)d_in[3];
  const float* w2 = (const float*)d_in[4];
  const float* b2 = (const float*)d_in[5];
  const float* w3 = (const float*)d_in[6];
  const float* b3 = (const float*)d_in[7];
  float* out = (float*)d_out;

  if (ws_size >= WS_NEEDED) {
    float* w1T = (float*)d_ws;
    float* pre1 = (float*)((char*)d_ws + PRE1_OFF);
    hipLaunchKernelGGL(transpose_w1, dim3((XS * HID + 255) / 256), dim3(256), 0, stream,
                       w1, w1T);
    hipLaunchKernelGGL(pre1_kernel, dim3(RTI_TOT / 4), dim3(256), 0, stream,
                       runs, w1T, b1, pre1);
    hipLaunchKernelGGL(seq_kernel, dim3(R_RUNS), dim3(64), 0, stream,
                       w1, w2, b2, w3, b3, comm_init, pre1, out);
  } else {
    hipLaunchKernelGGL(seq_fused, dim3(R_RUNS), dim3(64), 0, stream,
                       runs, comm_init, w1, b1, w2, b2, w3, b3, out);
  }
}

// Round 4
// 4348.307 us; speedup vs baseline: 1.7980x; 1.7980x over previous
//
#include <hip/hip_runtime.h>

// ---------------------------------------------------------------------------
// ComNet: R=16 runs x T=512 steps x 32 agents, sequential agent scan.
//   k0: transpose W1[:, :93] -> w1T
//   k1: pre1[rti][h] = SC*(b1[h] + xs(93) . W1xs)  (parallel, bulk of FLOPs)
//   k2: wave-synchronous sequential kernel, 16 blocks x 1 wave.
//   k3: out_kernel: o0/o1 = w3[0:2] . h2 (h2 spilled by k2), parallel.
// R6: fp16 h1 LDS + v_dot2 + clampless tanh + off-chain o0/o1: 6827->5520us.
// R7: pre1 t-rows staged through a double-buffered LDS ring. PROVEN 5569us.
// R8/R8b/R9: in-register h1 all-gather. R9 self-test PASSED on HW (primitives
//   verified) but ran 2264us SLOWER: ~75 dependent cross-lane VALU ops lose
//   to the LDS round trip. Gather abandoned; primitive semantics retained.
// R10: chain/issue diet with proven pieces only:
//   (a) c_sum reduce -> all-lanes butterfly (DPP ^1,^2,^7,^15 + pl16/pl32
//       swap-adds; order-invariant). No readlane/SGPR bubble.
//   (b) constants folded off-chain: SC=2*log2e baked into W1/b1/pre1/A/B and
//       f16 W2 weights -> both tanh's use exp2 directly; b32 folded into Qb2;
//       w32*h2 = fma(-2*w32, r2, w32).
//   (c) o0/o1 offloaded: h2 (f32) stored per step into consumed pre1 rows
//       (row t last read at iter t-2), out_kernel reduces afterwards.
// ---------------------------------------------------------------------------

#define R_RUNS 16
#define T_STEPS 512
#define NA 32
#define HID 64
#define XS 93                       // (NA-1)*3
#define DIN 124
#define STEPS_PER_RUN (T_STEPS * NA)        // 16384
#define RTI_TOT (R_RUNS * STEPS_PER_RUN)    // 262144

#define PRE1_OFF 65536
#define WS_NEEDED ((size_t)PRE1_OFF + (size_t)RTI_TOT * HID * 4 + 4096)

typedef _Float16 half2_t __attribute__((ext_vector_type(2)));
typedef unsigned int uint2v __attribute__((ext_vector_type(2)));

#if defined(__has_builtin)
#if __has_builtin(__builtin_amdgcn_permlane16_swap) && __has_builtin(__builtin_amdgcn_permlane32_swap)
#define HAVE_PLSWAP 1
#endif
#endif
#ifndef HAVE_PLSWAP
#define HAVE_PLSWAP 0
#endif

#if defined(__has_builtin)
#if __has_builtin(__builtin_amdgcn_exp2f)
#define EXPFN(x) __builtin_amdgcn_exp2f(x)
#define SC 2.8853900817779268f      // 2*log2(e): exp(2x) = exp2(SC*x)
#define HAVE_EXP2 1
#endif
#endif
#ifndef HAVE_EXP2
#define EXPFN(x) __expf(x)          // fallback: exp(2x) with SC=2
#define SC 2.0f
#define HAVE_EXP2 0
#endif

__device__ __forceinline__ float fast_tanh(float x) {
  // tanh(x) = 1 - 2/(e^{2x}+1); exp(+inf)->rcp(inf)=0 -> 1; exp(-inf)=0 -> -1.
  float e = __expf(2.f * x);
  return fmaf(-2.f, __builtin_amdgcn_rcpf(e + 1.f), 1.f);
}

__device__ __forceinline__ float dot2h(half2_t a, half2_t b, float c) {
#if __has_builtin(__builtin_amdgcn_fdot2)
  return __builtin_amdgcn_fdot2(a, b, c, false);
#else
  return fmaf((float)a.x, (float)b.x, fmaf((float)a.y, (float)b.y, c));
#endif
}

__device__ __forceinline__ half2_t bch(unsigned u) {
  return __builtin_bit_cast(half2_t, u);
}

#define DPP_ADD(x, ctrl, rmask) \
  (x) += __int_as_float(__builtin_amdgcn_update_dpp(0, __float_as_int(x), (ctrl), (rmask), 0xf, true))

// legacy shr-tree reduce (used by seq_fused and the non-plswap fallback)
__device__ __forceinline__ float wave64_sum_bcast(float x) {
  DPP_ADD(x, 0x111, 0xf);
  DPP_ADD(x, 0x112, 0xf);
  DPP_ADD(x, 0x114, 0xf);
  DPP_ADD(x, 0x118, 0xf);
  DPP_ADD(x, 0x142, 0xa);
  DPP_ADD(x, 0x143, 0xc);
  return __int_as_float(__builtin_amdgcn_readlane(__float_as_int(x), 63));
}

// all-lanes butterfly sum: DPP xor 1,2 + half/row mirror + permlane swaps.
// pl-swap result-pair order is irrelevant (both results are added).
__device__ __forceinline__ float wave64_sum_all(float x) {
  DPP_ADD(x, 0xB1, 0xf);    // quad_perm [1,0,3,2]  : ^1
  DPP_ADD(x, 0x4E, 0xf);    // quad_perm [2,3,0,1]  : ^2
  DPP_ADD(x, 0x141, 0xf);   // row_half_mirror      : pairs quads
  DPP_ADD(x, 0x140, 0xf);   // row_mirror           : pairs 8-halves
#if HAVE_PLSWAP
  uint2v p = __builtin_amdgcn_permlane16_swap(__float_as_uint(x), __float_as_uint(x), false, false);
  x = __uint_as_float(p[0]) + __uint_as_float(p[1]);
  p = __builtin_amdgcn_permlane32_swap(__float_as_uint(x), __float_as_uint(x), false, false);
  x = __uint_as_float(p[0]) + __uint_as_float(p[1]);
  return x;
#else
  DPP_ADD(x, 0x142, 0xa);   // row_bcast15
  DPP_ADD(x, 0x143, 0xc);   // row_bcast31
  return __int_as_float(__builtin_amdgcn_readlane(__float_as_int(x), 63));
#endif
}

// ---------------- k0: transpose W1 xs-part ----------------
__global__ void transpose_w1(const float* __restrict__ w1, float* __restrict__ w1T) {
  int idx = blockIdx.x * blockDim.x + threadIdx.x;  // idx = k*64 + h
  if (idx < XS * HID) {
    int k = idx / HID, h = idx % HID;
    w1T[idx] = w1[h * DIN + k];
  }
}

// ---------------- k1: pre1 = SC * (b1 + xs @ W1xs^T) ----------------
__global__ __launch_bounds__(256) void pre1_kernel(
    const float* __restrict__ runs, const float* __restrict__ w1T,
    const float* __restrict__ b1, float* __restrict__ pre1) {
  const int wid = (blockIdx.x * 256 + threadIdx.x) >> 6;  // rti, one wave each
  const int lane = threadIdx.x & 63;
  const float* xs = runs + (size_t)wid * XS;   // wave-uniform: broadcast loads
  float a0 = b1[lane], a1 = 0.f, a2 = 0.f;
#pragma unroll 4
  for (int k = 0; k < 31; ++k) {
    a0 = fmaf(xs[3 * k],     w1T[(3 * k) * HID + lane],     a0);
    a1 = fmaf(xs[3 * k + 1], w1T[(3 * k + 1) * HID + lane], a1);
    a2 = fmaf(xs[3 * k + 2], w1T[(3 * k + 2) * HID + lane], a2);
  }
  pre1[(size_t)wid * HID + lane] = SC * ((a0 + a1) + a2);
}

// ---------------- k3: o0/o1 from spilled h2 ----------------
__global__ __launch_bounds__(256) void out_kernel(
    const float* __restrict__ h2, const float* __restrict__ w3,
    const float* __restrict__ b3, float* __restrict__ out) {
  const int rti = blockIdx.x * 256 + threadIdx.x;
  const float4* hv4 = (const float4*)(h2 + (size_t)rti * HID);
  const float4* w0v = (const float4*)w3;
  const float4* w1v = (const float4*)(w3 + HID);
  float p00 = 0.f, p01 = 0.f, p02 = 0.f, p03 = 0.f;
  float p10 = 0.f, p11 = 0.f, p12 = 0.f, p13 = 0.f;
#pragma unroll
  for (int k = 0; k < 16; ++k) {
    float4 hv = hv4[k];
    float4 w0 = w0v[k];
    float4 w1r = w1v[k];
    p00 = fmaf(w0.x, hv.x, p00);  p01 = fmaf(w0.y, hv.y, p01);
    p02 = fmaf(w0.z, hv.z, p02);  p03 = fmaf(w0.w, hv.w, p03);
    p10 = fmaf(w1r.x, hv.x, p10); p11 = fmaf(w1r.y, hv.y, p11);
    p12 = fmaf(w1r.z, hv.z, p12); p13 = fmaf(w1r.w, hv.w, p13);
  }
  float o0 = ((p00 + p01) + (p02 + p03)) + b3[0];
  float o1 = ((p10 + p11) + (p12 + p13)) + b3[1];
  *(float2*)(out + (size_t)rti * 2) = make_float2(o0, o1);
}

// ---------------- k2: sequential core (wave-synchronous) ----------------
// A2[h][j] = SC*w1[h][93+j] (j<=30, pad 0), B2[h][j] = SC*w1[h][92+j] (j>=1).
// E(i) = SC*(pre-activation of step i) carried across steps:
//   E(i+1) = H + A2_i*csum_i,  H = pf2(i+1) + FB2 - S2(thru i+1) + Qb2,
//   Qb2 = Q2 + A2_i*b32,  Q2' = Qb2 + A2_i*csum_i.  All H-parts off-chain.
// pre1h2 is NOT restrict: consumed pre1 rows are reused as the h2 spill.
__global__ __launch_bounds__(64, 1) void seq_kernel(
    const float* __restrict__ w1, const float* __restrict__ w2,
    const float* __restrict__ b2, const float* __restrict__ w3,
    const float* __restrict__ b3, const float* __restrict__ comm_init,
    float* pre1h2) {
  const int h = threadIdx.x;
  const int r = blockIdx.x;
  const int hb = h * 33;              // stride 33: conflict-free, +pad entry 32

  __shared__ float Asl[HID * 33];
  __shared__ float Bsl[HID * 33];
  __shared__ __align__(16) float commL[NA];
  __shared__ __align__(16) _Float16 h1s16[HID];   // h1 broadcast buffer
  __shared__ __align__(16) float pbuf[2][2048 + 64];  // t-row ring + pad read slot

  for (int j = 0; j < 31; ++j) Asl[hb + j] = SC * w1[h * DIN + 93 + j];
  Asl[hb + 31] = 0.f;
  Asl[hb + 32] = 0.f;                 // pad: A_next read at i=31
  Bsl[hb] = 0.f;
  for (int j = 1; j < 32; ++j) Bsl[hb + j] = SC * w1[h * DIN + 92 + j];
  Bsl[hb + 32] = 0.f;                 // pad: B_next read at i=31

  // W2 row h -> 32 NAMED half2, scaled by SC (no array -> no SROA demotion).
  const float4* w2v = (const float4*)(w2 + h * HID);
  const float4 r0 = w2v[0],  r1 = w2v[1],  r2 = w2v[2],  r3 = w2v[3];
  const float4 r4 = w2v[4],  r5 = w2v[5],  r6 = w2v[6],  r7 = w2v[7];
  const float4 r8 = w2v[8],  r9 = w2v[9],  r10 = w2v[10], r11 = w2v[11];
  const float4 r12 = w2v[12], r13 = w2v[13], r14 = w2v[14], r15 = w2v[15];
#define PK2S(n, f4) \
  const half2_t n##a = {(_Float16)(SC * (f4).x), (_Float16)(SC * (f4).y)}; \
  const half2_t n##b = {(_Float16)(SC * (f4).z), (_Float16)(SC * (f4).w)}
  PK2S(q0, r0);  PK2S(q1, r1);  PK2S(q2, r2);  PK2S(q3, r3);
  PK2S(q4, r4);  PK2S(q5, r5);  PK2S(q6, r6);  PK2S(q7, r7);
  PK2S(q8, r8);  PK2S(q9, r9);  PK2S(q10, r10); PK2S(q11, r11);
  PK2S(q12, r12); PK2S(q13, r13); PK2S(q14, r14); PK2S(q15, r15);
#undef PK2S

  const float b2s = SC * b2[h];
  const float w32h = w3[2 * HID + h];
  const float w32n2 = -2.f * w32h;    // w32*h2 = fma(w32n2, r2, w32h)
  const float b32 = b3[2];

  float commR = (h < NA) ? comm_init[r * NA + h] : 0.f;  // lane j holds comm[j]
  if (h < NA) commL[h] = commR;                          // mirror for FB refresh

  float* prow = pre1h2 + (size_t)r * STEPS_PER_RUN * HID;  // + t*2048 floats

  // prime rows 0 and 1 into the LDS ring (one-time)
  {
    const float4* s0 = (const float4*)prow;
    const float4* s1 = (const float4*)(prow + 2048);
    float4* d0 = (float4*)&pbuf[0][0];
    float4* d1 = (float4*)&pbuf[1][0];
#pragma unroll
    for (int j = 0; j < 8; ++j) d0[j * 64 + h] = s0[j * 64 + h];
#pragma unroll
    for (int j = 0; j < 8; ++j) d1[j * 64 + h] = s1[j * 64 + h];
  }

  for (int t = 0; t < T_STEPS; ++t) {
    float* pb = pbuf[t & 1];
    // prefetch row t+2 into 8 named float4 regs; retires during the long body;
    // consumed by the ds_writes at the end of this t. Fully off-chain.
    int tk = (t + 2 <= T_STEPS - 1) ? t + 2 : T_STEPS - 1;
    const float4* gsrc = (const float4*)(prow + (size_t)tk * 2048);
    float4 g0 = gsrc[0 * 64 + h], g1 = gsrc[1 * 64 + h];
    float4 g2 = gsrc[2 * 64 + h], g3 = gsrc[3 * 64 + h];
    float4 g4 = gsrc[4 * 64 + h], g5 = gsrc[5 * 64 + h];
    float4 g6 = gsrc[6 * 64 + h], g7 = gsrc[7 * 64 + h];

    // FB2 refresh (amortized over 32 steps); commL finalized at end of t-1.
    const float4* cv4 = (const float4*)commL;
    float f0 = 0.f, f1 = 0.f, f2 = 0.f, f3 = 0.f;
#pragma unroll
    for (int q = 0; q < 8; ++q) {
      float4 c = cv4[q];
      f0 = fmaf(Bsl[hb + 4 * q + 0], c.x, f0);
      f1 = fmaf(Bsl[hb + 4 * q + 1], c.y, f1);
      f2 = fmaf(Bsl[hb + 4 * q + 2], c.z, f2);
      f3 = fmaf(Bsl[hb + 4 * q + 3], c.w, f3);
    }
    const float FB2 = (f0 + f1) + (f2 + f3);
    const float c0s = commR;           // t-start snapshot: old_i source, off-chain
    float Q2 = 0.f, S2 = 0.f;
    float A2_c = Asl[hb];
    float E = pb[h] + FB2;             // step-0 pre-act (B[h][0]=0 -> S term 0)
    float* h2t = prow + (size_t)t * 2048;   // h2 spill: reuses consumed row t

#pragma unroll 4
    for (int i = 0; i < NA; ++i) {
      // 1-ahead pipelined LDS reads (i=31 hits the pad slot / entry 32 -> 0)
      float pf2_n = pb[(i + 1) * 64 + h];
      float A2_n = Asl[hb + i + 1];
      float B2_n = Bsl[hb + i + 1];
      float old_n = __int_as_float(__builtin_amdgcn_readlane(__float_as_int(c0s), i + 1));
      // ---- on-chain: h1 from carried E ----
      float e1 = EXPFN(E);
      float r1v = __builtin_amdgcn_rcpf(e1 + 1.f);
      float h1 = fmaf(-2.f, r1v, 1.f);
      h1s16[h] = (_Float16)h1;
      // ---- off-chain while the LDS broadcast round-trips ----
      float S2n = fmaf(B2_n, old_n, S2);        // S2 through i+1
      float Qb2 = fmaf(A2_c, b32, Q2);          // Q2 + A2_i*b32
      float H = pf2_n + (FB2 - S2n) + Qb2;
      // ---- dots: 64-term, 32 v_dot2, 4 chains; weights pre-scaled by SC ----
      const uint4* hv = (const uint4*)h1s16;    // broadcast reads, 8 b128
      uint4 X0 = hv[0], X1 = hv[1], X2 = hv[2], X3 = hv[3];
      uint4 X4 = hv[4], X5 = hv[5], X6 = hv[6], X7 = hv[7];
      float a0 = b2s, a1 = 0.f, a2 = 0.f, a3 = 0.f;
#define DOTB(Xq, qe, qo) \
      a0 = dot2h(qe##a, bch(Xq.x), a0); a1 = dot2h(qe##b, bch(Xq.y), a1); \
      a2 = dot2h(qo##a, bch(Xq.z), a2); a3 = dot2h(qo##b, bch(Xq.w), a3)
      DOTB(X0, q0, q1);   DOTB(X1, q2, q3);
      DOTB(X2, q4, q5);   DOTB(X3, q6, q7);
      DOTB(X4, q8, q9);   DOTB(X5, q10, q11);
      DOTB(X6, q12, q13); DOTB(X7, q14, q15);
#undef DOTB
      float y2 = (a0 + a1) + (a2 + a3);         // = SC * layer2 pre-act
      float e2 = EXPFN(y2);
      float r2v = __builtin_amdgcn_rcpf(e2 + 1.f);
      float xr = fmaf(w32n2, r2v, w32h);        // = w32h * h2
      float csum = wave64_sum_all(xr);          // all lanes, no readlane
      // ---- off-chain epilogue ----
      float h2v = fmaf(-2.f, r2v, 1.f);
      h2t[i * 64 + h] = h2v;                    // coalesced 256B spill
      float c_new = csum + b32;
      commR = (h == i) ? c_new : commR;
      E = fmaf(A2_c, csum, H);                  // next step's pre-act (chain)
      Q2 = fmaf(A2_c, csum, Qb2);               // feeds next H (off-chain)
      S2 = S2n; A2_c = A2_n;
    }
    if (h < NA) commL[h] = commR;      // mirror refresh, once per t
    // stage row t+2 into the buffer just freed (all reads of pb are done;
    // g-regs loaded a full body ago -> no vmcnt stall).
    float4* pd = (float4*)pb;
    pd[0 * 64 + h] = g0; pd[1 * 64 + h] = g1;
    pd[2 * 64 + h] = g2; pd[3 * 64 + h] = g3;
    pd[4 * 64 + h] = g4; pd[5 * 64 + h] = g5;
    pd[6 * 64 + h] = g6; pd[7 * 64 + h] = g7;
  }
}

// ---------------- fallback: fully fused, zero workspace (unused when ws ok) --
__global__ __launch_bounds__(64, 1) void seq_fused(
    const float* __restrict__ runs, const float* __restrict__ comm_init,
    const float* __restrict__ w1, const float* __restrict__ b1,
    const float* __restrict__ w2, const float* __restrict__ b2,
    const float* __restrict__ w3, const float* __restrict__ b3,
    float* __restrict__ out) {
  const int r = blockIdx.x;
  const int h = threadIdx.x;
  const int hb = h * 33;

  __shared__ float Asl[HID * 33];
  __shared__ float Bsl[HID * 33];
  __shared__ float commL[NA];
  __shared__ __align__(16) float h1s[HID];
  __shared__ float w1xs[XS * HID];
  __shared__ __align__(16) float xsl[96];

  for (int j = 0; j < 31; ++j) Asl[hb + j] = w1[h * DIN + 93 + j];
  Asl[hb + 31] = 0.f;
  Bsl[hb] = 0.f;
  for (int j = 1; j < 32; ++j) Bsl[hb + j] = w1[h * DIN + 92 + j];
  for (int k = 0; k < XS; ++k) w1xs[k * HID + h] = w1[h * DIN + k];

  float w2r[HID];
#pragma unroll
  for (int k = 0; k < HID; ++k) w2r[k] = w2[h * HID + k];
  const float b1h = b1[h];
  const float b2h = b2[h];
  const float w30h = w3[h], w31h = w3[HID + h], w32h = w3[2 * HID + h];
  const float b30 = b3[0], b31 = b3[1], b32 = b3[2];
  if (h < NA) commL[h] = comm_init[r * NA + h];

  const float* xbase = runs + (size_t)r * STEPS_PER_RUN * XS;
  float xa = xbase[h];
  float xb = (h < XS - 64) ? xbase[64 + h] : 0.f;
  float* outp = out + (size_t)r * STEPS_PER_RUN * 2;
  __syncthreads();

  int s = 0;
  for (int t = 0; t < T_STEPS; ++t) {
    float FB = 0.f;
#pragma unroll
    for (int j = 0; j < NA; ++j) FB = fmaf(Bsl[hb + j], commL[j], FB);
    float Q = 0.f, S = 0.f;
    for (int i = 0; i < NA; ++i, ++s) {
      int sn = s + 1; if (sn > STEPS_PER_RUN - 1) sn = STEPS_PER_RUN - 1;
      const float* xn = xbase + (size_t)sn * XS;
      xsl[h] = xa;
      if (h < XS - 64) xsl[64 + h] = xb;
      __syncthreads();
      float xa_n = xn[h];
      float xb_n = (h < XS - 64) ? xn[64 + h] : 0.f;
      float a0 = b1h, a1 = 0.f, a2 = 0.f;
#pragma unroll 4
      for (int k = 0; k < 31; ++k) {
        a0 = fmaf(xsl[3 * k],     w1xs[(3 * k) * HID + h],     a0);
        a1 = fmaf(xsl[3 * k + 1], w1xs[(3 * k + 1) * HID + h], a1);
        a2 = fmaf(xsl[3 * k + 2], w1xs[(3 * k + 2) * HID + h], a2);
      }
      float old_i = commL[i];
      S = fmaf(Bsl[hb + i], old_i, S);
      float h1 = fast_tanh(((a0 + a1) + a2) + FB + Q - S);
      h1s[h] = h1;
      __syncthreads();
      float c0 = b2h, c1 = 0.f, c2 = 0.f, c3 = 0.f;
      const float4* hv4 = (const float4*)h1s;
#pragma unroll
      for (int k4 = 0; k4 < 16; ++k4) {
        float4 hv = hv4[k4];
        c0 = fmaf(w2r[4 * k4 + 0], hv.x, c0);
        c1 = fmaf(w2r[4 * k4 + 1], hv.y, c1);
        c2 = fmaf(w2r[4 * k4 + 2], hv.z, c2);
        c3 = fmaf(w2r[4 * k4 + 3], hv.w, c3);
      }
      float h2 = fast_tanh((c0 + c1) + (c2 + c3));
      float o0 = wave64_sum_bcast(w30h * h2) + b30;
      float o1 = wave64_sum_bcast(w31h * h2) + b31;
      float c_new = wave64_sum_bcast(w32h * h2) + b32;
      if (h == 0) *(float2*)(outp + (size_t)s * 2) = make_float2(o0, o1);
      Q = fmaf(Asl[hb + i], c_new, Q);
      if (h == i) commL[h] = c_new;
      __syncthreads();
      xa = xa_n; xb = xb_n;
    }
  }
}

extern "C" void kernel_launch(void* const* d_in, const int* in_sizes, int n_in,
                              void* d_out, int out_size, void* d_ws, size_t ws_size,
                              hipStream_t stream) {
  const float* runs = (const float*)d_in[0];
  const float* comm_init = (const float*)d_in[1];
  const float* w1 = (const float*)d_in[2];
  const float* b1 = (const float*)d_in[3];
  const float* w2 = (const float*)d_in[4];
  const float* b2 = (const float*)d_in[5];
  const float* w3 = (const float*)d_in[6];
  const float* b3 = (const float*)d_in[7];
  float* out = (float*)d_out;

  if (ws_size >= WS_NEEDED) {
    float* w1T = (float*)d_ws;
    float* pre1 = (float*)((char*)d_ws + PRE1_OFF);
    hipLaunchKernelGGL(transpose_w1, dim3((XS * HID + 255) / 256), dim3(256), 0, stream,
                       w1, w1T);
    hipLaunchKernelGGL(pre1_kernel, dim3(RTI_TOT / 4), dim3(256), 0, stream,
                       runs, w1T, b1, pre1);
    hipLaunchKernelGGL(seq_kernel, dim3(R_RUNS), dim3(64), 0, stream,
                       w1, w2, b2, w3, b3, comm_init, pre1);
    hipLaunchKernelGGL(out_kernel, dim3(RTI_TOT / 256), dim3(256), 0, stream,
                       pre1, w3, b3, out);
  } else {
    hipLaunchKernelGGL(seq_fused, dim3(R_RUNS), dim3(64), 0, stream,
                       runs, comm_init, w1, b1, w2, b2, w3, b3, out);
  }
}

// Round 7
// 4320.749 us; speedup vs baseline: 1.8094x; 1.0064x over previous
//
#include <hip/hip_runtime.h>

// ---------------------------------------------------------------------------
// ComNet: R=16 runs x T=512 steps x 32 agents, sequential agent scan.
//   k0: repack W1[:, :93] -> w1T4 [24][64][4] (k padded to 96 with zeros)
//   k1: pre1[rti][h] = SC*(b1[h] + xs(93) . W1xs)  (reg-blocked, 4 rti/wave)
//   k2: wave-synchronous sequential kernel, 16 blocks x 1 wave.
//   k3: out_kernel: o0/o1 = w3[0:2] . h2 (h2 spilled by k2), parallel.
// R7: pre1 LDS ring, no global near chain. PROVEN 5569us total.
// R9: register all-gather self-test PASSED (primitive semantics HW-verified:
//   pl32swap(a,a)[0][l]=a[l&31], [1][l]=a[l|32]; pl16swap analogous) but the
//   full-tree gather was SLOWER. Tree abandoned; semantics reused.
// R10: exp2-folded activations (SC scaling), all-lanes butterfly csum,
//   h2 spill + separate out_kernel: 5049 -> 3819us seq, 4348 total.
// R11: (a) 2-way split-K W2 dot: lane l reads only its h1 half (4 b128, not
//   8), computes partials for rows l and l^32, combines with ONE verified
//   permlane32_swap + cndmask + add. (b) pre1 reg-blocked: w1 as 24 float4
//   in regs, 4 rti/wave -> 93 VMEM/rti -> ~6.
// R12/R13: identical resubmits of R11. R5 and R6 benches both died at
//   container ACQUISITION (no timing block -> failure precedes compile/push;
//   kernel-independent infra flake). If R13 also fails at acquisition,
//   fall back to proven R10 source to re-baseline the bench path.
// ---------------------------------------------------------------------------

#define R_RUNS 16
#define T_STEPS 512
#define NA 32
#define HID 64
#define XS 93                       // (NA-1)*3
#define DIN 124
#define STEPS_PER_RUN (T_STEPS * NA)        // 16384
#define RTI_TOT (R_RUNS * STEPS_PER_RUN)    // 262144

#define PRE1_OFF 65536
#define WS_NEEDED ((size_t)PRE1_OFF + (size_t)RTI_TOT * HID * 4 + 4096)

typedef _Float16 half2_t __attribute__((ext_vector_type(2)));
typedef unsigned int uint2v __attribute__((ext_vector_type(2)));

#if defined(__has_builtin)
#if __has_builtin(__builtin_amdgcn_permlane16_swap) && __has_builtin(__builtin_amdgcn_permlane32_swap)
#define HAVE_PLSWAP 1
#endif
#endif
#ifndef HAVE_PLSWAP
#define HAVE_PLSWAP 0
#endif

#if defined(__has_builtin)
#if __has_builtin(__builtin_amdgcn_exp2f)
#define EXPFN(x) __builtin_amdgcn_exp2f(x)
#define SC 2.8853900817779268f      // 2*log2(e): exp(2x) = exp2(SC*x)
#define HAVE_EXP2 1
#endif
#endif
#ifndef HAVE_EXP2
#define EXPFN(x) __expf(x)          // fallback: exp(2x) with SC=2
#define SC 2.0f
#define HAVE_EXP2 0
#endif

__device__ __forceinline__ float fast_tanh(float x) {
  // tanh(x) = 1 - 2/(e^{2x}+1); exp(+inf)->rcp(inf)=0 -> 1; exp(-inf)=0 -> -1.
  float e = __expf(2.f * x);
  return fmaf(-2.f, __builtin_amdgcn_rcpf(e + 1.f), 1.f);
}

__device__ __forceinline__ float dot2h(half2_t a, half2_t b, float c) {
#if __has_builtin(__builtin_amdgcn_fdot2)
  return __builtin_amdgcn_fdot2(a, b, c, false);
#else
  return fmaf((float)a.x, (float)b.x, fmaf((float)a.y, (float)b.y, c));
#endif
}

__device__ __forceinline__ half2_t bch(unsigned u) {
  return __builtin_bit_cast(half2_t, u);
}

#define DPP_ADD(x, ctrl, rmask) \
  (x) += __int_as_float(__builtin_amdgcn_update_dpp(0, __float_as_int(x), (ctrl), (rmask), 0xf, true))

// legacy shr-tree reduce (used by seq_fused)
__device__ __forceinline__ float wave64_sum_bcast(float x) {
  DPP_ADD(x, 0x111, 0xf);
  DPP_ADD(x, 0x112, 0xf);
  DPP_ADD(x, 0x114, 0xf);
  DPP_ADD(x, 0x118, 0xf);
  DPP_ADD(x, 0x142, 0xa);
  DPP_ADD(x, 0x143, 0xc);
  return __int_as_float(__builtin_amdgcn_readlane(__float_as_int(x), 63));
}

// all-lanes butterfly sum: DPP xor 1,2 + half/row mirror + permlane swaps.
// pl-swap result-pair order irrelevant here (both results are added).
__device__ __forceinline__ float wave64_sum_all(float x) {
  DPP_ADD(x, 0xB1, 0xf);    // quad_perm [1,0,3,2]  : ^1
  DPP_ADD(x, 0x4E, 0xf);    // quad_perm [2,3,0,1]  : ^2
  DPP_ADD(x, 0x141, 0xf);   // row_half_mirror      : pairs quads
  DPP_ADD(x, 0x140, 0xf);   // row_mirror           : pairs 8-halves
#if HAVE_PLSWAP
  uint2v p = __builtin_amdgcn_permlane16_swap(__float_as_uint(x), __float_as_uint(x), false, false);
  x = __uint_as_float(p[0]) + __uint_as_float(p[1]);
  p = __builtin_amdgcn_permlane32_swap(__float_as_uint(x), __float_as_uint(x), false, false);
  x = __uint_as_float(p[0]) + __uint_as_float(p[1]);
  return x;
#else
  DPP_ADD(x, 0x142, 0xa);   // row_bcast15
  DPP_ADD(x, 0x143, 0xc);   // row_bcast31
  return __int_as_float(__builtin_amdgcn_readlane(__float_as_int(x), 63));
#endif
}

// ---------------- k0: repack W1 xs-part -> [24][64][4], zero-padded --------
__global__ void transpose_w1(const float* __restrict__ w1, float* __restrict__ w1T4) {
  int idx = blockIdx.x * blockDim.x + threadIdx.x;  // (kk*64+h)*4+c
  if (idx < 24 * HID * 4) {
    int c = idx & 3, h = (idx >> 2) & 63, kk = idx >> 8;
    int k = 4 * kk + c;
    w1T4[idx] = (k < XS) ? w1[h * DIN + k] : 0.f;
  }
}

// ---------------- k1: pre1 = SC * (b1 + xs @ W1xs^T), reg-blocked ----------
#define PRE1_BATCH 4
__global__ __launch_bounds__(256) void pre1_kernel(
    const float* __restrict__ runs, const float* __restrict__ w1T4,
    const float* __restrict__ b1, float* __restrict__ pre1) {
  const int wid = (blockIdx.x * 256 + threadIdx.x) >> 6;  // wave id
  const int lane = threadIdx.x & 63;
  const int rti0 = wid * PRE1_BATCH;
  const float4* wv = (const float4*)w1T4;
  float4 w[24];                      // full unroll -> static indices -> regs
#pragma unroll
  for (int kk = 0; kk < 24; ++kk) w[kk] = wv[kk * 64 + lane];
  const float b1s = b1[lane];
#pragma unroll
  for (int u = 0; u < PRE1_BATCH; ++u) {
    const float* xs = runs + (size_t)(rti0 + u) * XS;  // wave-uniform loads
    float a0 = b1s, a1 = 0.f, a2 = 0.f, a3 = 0.f;
#pragma unroll
    for (int kk = 0; kk < 23; ++kk) {
      a0 = fmaf(xs[4 * kk + 0], w[kk].x, a0);
      a1 = fmaf(xs[4 * kk + 1], w[kk].y, a1);
      a2 = fmaf(xs[4 * kk + 2], w[kk].z, a2);
      a3 = fmaf(xs[4 * kk + 3], w[kk].w, a3);
    }
    a0 = fmaf(xs[92], w[23].x, a0);  // k=93..95 are zero-pad; no OOB xs read
    pre1[(size_t)(rti0 + u) * HID + lane] = SC * ((a0 + a1) + (a2 + a3));
  }
}

// ---------------- k3: o0/o1 from spilled h2 ----------------
__global__ __launch_bounds__(256) void out_kernel(
    const float* __restrict__ h2, const float* __restrict__ w3,
    const float* __restrict__ b3, float* __restrict__ out) {
  const int rti = blockIdx.x * 256 + threadIdx.x;
  const float4* hv4 = (const float4*)(h2 + (size_t)rti * HID);
  const float4* w0v = (const float4*)w3;
  const float4* w1v = (const float4*)(w3 + HID);
  float p00 = 0.f, p01 = 0.f, p02 = 0.f, p03 = 0.f;
  float p10 = 0.f, p11 = 0.f, p12 = 0.f, p13 = 0.f;
#pragma unroll
  for (int k = 0; k < 16; ++k) {
    float4 hv = hv4[k];
    float4 w0 = w0v[k];
    float4 w1r = w1v[k];
    p00 = fmaf(w0.x, hv.x, p00);  p01 = fmaf(w0.y, hv.y, p01);
    p02 = fmaf(w0.z, hv.z, p02);  p03 = fmaf(w0.w, hv.w, p03);
    p10 = fmaf(w1r.x, hv.x, p10); p11 = fmaf(w1r.y, hv.y, p11);
    p12 = fmaf(w1r.z, hv.z, p12); p13 = fmaf(w1r.w, hv.w, p13);
  }
  float o0 = ((p00 + p01) + (p02 + p03)) + b3[0];
  float o1 = ((p10 + p11) + (p12 + p13)) + b3[1];
  *(float2*)(out + (size_t)rti * 2) = make_float2(o0, o1);
}

// ---------------- k2: sequential core (wave-synchronous) ----------------
// A2[h][j] = SC*w1[h][93+j] (j<=30, pad 0), B2[h][j] = SC*w1[h][92+j] (j>=1).
// E(i) carried across steps; all H-parts off-chain (see R10 notes).
// W2 dot is 2-way split-K: lane l covers h1[hi*32..+31] (hi=l>>5) for output
// rows l and l^32; partner partial fetched with permlane32_swap (verified:
// sw[0][l]=x[l&31], sw[1][l]=x[l|32]) and selected by hi.
// pre1h2 is NOT restrict: consumed pre1 rows are reused as the h2 spill.
__global__ __launch_bounds__(64, 1) void seq_kernel(
    const float* __restrict__ w1, const float* __restrict__ w2,
    const float* __restrict__ b2, const float* __restrict__ w3,
    const float* __restrict__ b3, const float* __restrict__ comm_init,
    float* pre1h2) {
  const int h = threadIdx.x;
  const int r = blockIdx.x;
  const int hb = h * 33;              // stride 33: conflict-free, +pad entry 32

  __shared__ float Asl[HID * 33];
  __shared__ float Bsl[HID * 33];
  __shared__ __align__(16) float commL[NA];
  __shared__ __align__(16) _Float16 h1s16[HID];   // h1 broadcast buffer
  __shared__ __align__(16) float pbuf[2][2048 + 64];  // t-row ring + pad read slot

  for (int j = 0; j < 31; ++j) Asl[hb + j] = SC * w1[h * DIN + 93 + j];
  Asl[hb + 31] = 0.f;
  Asl[hb + 32] = 0.f;                 // pad: A_next read at i=31
  Bsl[hb] = 0.f;
  for (int j = 1; j < 32; ++j) Bsl[hb + j] = SC * w1[h * DIN + 92 + j];
  Bsl[hb + 32] = 0.f;                 // pad: B_next read at i=31

#if HAVE_PLSWAP
  // ---- R11 split-K weights: rows h and h^32, columns [hi*32, hi*32+32) ----
  const int hi = h >> 5;
  const float4* wA = (const float4*)(w2 + h * HID + hi * 32);
  const float4* wB = (const float4*)(w2 + (h ^ 32) * HID + hi * 32);
  const float4 A0 = wA[0], A1 = wA[1], A2v = wA[2], A3 = wA[3];
  const float4 A4 = wA[4], A5 = wA[5], A6 = wA[6], A7 = wA[7];
  const float4 B0 = wB[0], B1 = wB[1], B2v = wB[2], B3 = wB[3];
  const float4 B4 = wB[4], B5 = wB[5], B6 = wB[6], B7 = wB[7];
#define PK2S(n, f4) \
  const half2_t n##a = {(_Float16)(SC * (f4).x), (_Float16)(SC * (f4).y)}; \
  const half2_t n##b = {(_Float16)(SC * (f4).z), (_Float16)(SC * (f4).w)}
  PK2S(pa0, A0); PK2S(pa1, A1); PK2S(pa2, A2v); PK2S(pa3, A3);
  PK2S(pa4, A4); PK2S(pa5, A5); PK2S(pa6, A6);  PK2S(pa7, A7);
  PK2S(pb0, B0); PK2S(pb1, B1); PK2S(pb2, B2v); PK2S(pb3, B3);
  PK2S(pb4, B4); PK2S(pb5, B5); PK2S(pb6, B6);  PK2S(pb7, B7);
#undef PK2S
#else
  // fallback: full row h, 8-read broadcast (R10 form)
  const float4* w2v = (const float4*)(w2 + h * HID);
  const float4 r0 = w2v[0],  r1 = w2v[1],  r2 = w2v[2],  r3 = w2v[3];
  const float4 r4 = w2v[4],  r5 = w2v[5],  r6 = w2v[6],  r7 = w2v[7];
  const float4 r8 = w2v[8],  r9 = w2v[9],  r10 = w2v[10], r11 = w2v[11];
  const float4 r12 = w2v[12], r13 = w2v[13], r14 = w2v[14], r15 = w2v[15];
#define PK2S(n, f4) \
  const half2_t n##a = {(_Float16)(SC * (f4).x), (_Float16)(SC * (f4).y)}; \
  const half2_t n##b = {(_Float16)(SC * (f4).z), (_Float16)(SC * (f4).w)}
  PK2S(q0, r0);  PK2S(q1, r1);  PK2S(q2, r2);  PK2S(q3, r3);
  PK2S(q4, r4);  PK2S(q5, r5);  PK2S(q6, r6);  PK2S(q7, r7);
  PK2S(q8, r8);  PK2S(q9, r9);  PK2S(q10, r10); PK2S(q11, r11);
  PK2S(q12, r12); PK2S(q13, r13); PK2S(q14, r14); PK2S(q15, r15);
#undef PK2S
#endif

  const float b2s = SC * b2[h];
  const float w32h = w3[2 * HID + h];
  const float w32n2 = -2.f * w32h;    // w32*h2 = fma(w32n2, r2, w32h)
  const float b32 = b3[2];

  float commR = (h < NA) ? comm_init[r * NA + h] : 0.f;  // lane j holds comm[j]
  if (h < NA) commL[h] = commR;                          // mirror for FB refresh

  float* prow = pre1h2 + (size_t)r * STEPS_PER_RUN * HID;  // + t*2048 floats

  // prime rows 0 and 1 into the LDS ring (one-time)
  {
    const float4* s0 = (const float4*)prow;
    const float4* s1 = (const float4*)(prow + 2048);
    float4* d0 = (float4*)&pbuf[0][0];
    float4* d1 = (float4*)&pbuf[1][0];
#pragma unroll
    for (int j = 0; j < 8; ++j) d0[j * 64 + h] = s0[j * 64 + h];
#pragma unroll
    for (int j = 0; j < 8; ++j) d1[j * 64 + h] = s1[j * 64 + h];
  }

  for (int t = 0; t < T_STEPS; ++t) {
    float* pb = pbuf[t & 1];
    // prefetch row t+2 into 8 named float4 regs; retires during the long body;
    // consumed by the ds_writes at the end of this t. Fully off-chain.
    int tk = (t + 2 <= T_STEPS - 1) ? t + 2 : T_STEPS - 1;
    const float4* gsrc = (const float4*)(prow + (size_t)tk * 2048);
    float4 g0 = gsrc[0 * 64 + h], g1 = gsrc[1 * 64 + h];
    float4 g2 = gsrc[2 * 64 + h], g3 = gsrc[3 * 64 + h];
    float4 g4 = gsrc[4 * 64 + h], g5 = gsrc[5 * 64 + h];
    float4 g6 = gsrc[6 * 64 + h], g7 = gsrc[7 * 64 + h];

    // FB2 refresh (amortized over 32 steps); commL finalized at end of t-1.
    const float4* cv4 = (const float4*)commL;
    float f0 = 0.f, f1 = 0.f, f2 = 0.f, f3 = 0.f;
#pragma unroll
    for (int q = 0; q < 8; ++q) {
      float4 c = cv4[q];
      f0 = fmaf(Bsl[hb + 4 * q + 0], c.x, f0);
      f1 = fmaf(Bsl[hb + 4 * q + 1], c.y, f1);
      f2 = fmaf(Bsl[hb + 4 * q + 2], c.z, f2);
      f3 = fmaf(Bsl[hb + 4 * q + 3], c.w, f3);
    }
    const float FB2 = (f0 + f1) + (f2 + f3);
    const float c0s = commR;           // t-start snapshot: old_i source, off-chain
    float Q2 = 0.f, S2 = 0.f;
    float A2_c = Asl[hb];
    float E = pb[h] + FB2;             // step-0 pre-act (B[h][0]=0 -> S term 0)
    float* h2t = prow + (size_t)t * 2048;   // h2 spill: reuses consumed row t

#pragma unroll 4
    for (int i = 0; i < NA; ++i) {
      // 1-ahead pipelined LDS reads (i=31 hits the pad slot / entry 32 -> 0)
      float pf2_n = pb[(i + 1) * 64 + h];
      float A2_n = Asl[hb + i + 1];
      float B2_n = Bsl[hb + i + 1];
      float old_n = __int_as_float(__builtin_amdgcn_readlane(__float_as_int(c0s), i + 1));
      // ---- on-chain: h1 from carried E ----
      float e1 = EXPFN(E);
      float r1v = __builtin_amdgcn_rcpf(e1 + 1.f);
      float h1 = fmaf(-2.f, r1v, 1.f);
      h1s16[h] = (_Float16)h1;
      // ---- off-chain while the LDS broadcast round-trips ----
      float S2n = fmaf(B2_n, old_n, S2);        // S2 through i+1
      float Qb2 = fmaf(A2_c, b32, Q2);          // Q2 + A2_i*b32
      float H = pf2_n + (FB2 - S2n) + Qb2;
      float y2;
#if HAVE_PLSWAP
      // ---- split-K dots: 4 b128 reads (own half), 32 v_dot2, 4 chains ----
      const uint4* hv = (const uint4*)h1s16;
      uint4 X0 = hv[hi * 4 + 0], X1 = hv[hi * 4 + 1];
      uint4 X2 = hv[hi * 4 + 2], X3 = hv[hi * 4 + 3];
      float a0 = b2s, a1 = 0.f, a2 = 0.f, a3 = 0.f;
#define DOTP(Xq, e, o) \
      a0 = dot2h(pa##e##a, bch(Xq.x), a0); a2 = dot2h(pb##e##a, bch(Xq.x), a2); \
      a1 = dot2h(pa##e##b, bch(Xq.y), a1); a3 = dot2h(pb##e##b, bch(Xq.y), a3); \
      a0 = dot2h(pa##o##a, bch(Xq.z), a0); a2 = dot2h(pb##o##a, bch(Xq.z), a2); \
      a1 = dot2h(pa##o##b, bch(Xq.w), a1); a3 = dot2h(pb##o##b, bch(Xq.w), a3)
      DOTP(X0, 0, 1); DOTP(X1, 2, 3); DOTP(X2, 4, 5); DOTP(X3, 6, 7);
#undef DOTP
      float pA = a0 + a1;                       // own-row partial (+b2s)
      float pBo = a2 + a3;                      // partner-row partial
      uint2v sw = __builtin_amdgcn_permlane32_swap(
          __float_as_uint(pBo), __float_as_uint(pBo), false, false);
      float pB = hi ? __uint_as_float(sw[0]) : __uint_as_float(sw[1]);
      y2 = pA + pB;                             // = SC * layer2 pre-act
#else
      const uint4* hv = (const uint4*)h1s16;    // broadcast reads, 8 b128
      uint4 X0 = hv[0], X1 = hv[1], X2 = hv[2], X3 = hv[3];
      uint4 X4 = hv[4], X5 = hv[5], X6 = hv[6], X7 = hv[7];
      float a0 = b2s, a1 = 0.f, a2 = 0.f, a3 = 0.f;
#define DOTB(Xq, qe, qo) \
      a0 = dot2h(qe##a, bch(Xq.x), a0); a1 = dot2h(qe##b, bch(Xq.y), a1); \
      a2 = dot2h(qo##a, bch(Xq.z), a2); a3 = dot2h(qo##b, bch(Xq.w), a3)
      DOTB(X0, q0, q1);   DOTB(X1, q2, q3);
      DOTB(X2, q4, q5);   DOTB(X3, q6, q7);
      DOTB(X4, q8, q9);   DOTB(X5, q10, q11);
      DOTB(X6, q12, q13); DOTB(X7, q14, q15);
#undef DOTB
      y2 = (a0 + a1) + (a2 + a3);
#endif
      float e2 = EXPFN(y2);
      float r2v = __builtin_amdgcn_rcpf(e2 + 1.f);
      float xr = fmaf(w32n2, r2v, w32h);        // = w32h * h2
      float csum = wave64_sum_all(xr);          // all lanes, no readlane
      // ---- off-chain epilogue ----
      float h2v = fmaf(-2.f, r2v, 1.f);
      h2t[i * 64 + h] = h2v;                    // coalesced 256B spill
      float c_new = csum + b32;
      commR = (h == i) ? c_new : commR;
      E = fmaf(A2_c, csum, H);                  // next step's pre-act (chain)
      Q2 = fmaf(A2_c, csum, Qb2);               // feeds next H (off-chain)
      S2 = S2n; A2_c = A2_n;
    }
    if (h < NA) commL[h] = commR;      // mirror refresh, once per t
    // stage row t+2 into the buffer just freed (all reads of pb are done;
    // g-regs loaded a full body ago -> no vmcnt stall).
    float4* pd = (float4*)pb;
    pd[0 * 64 + h] = g0; pd[1 * 64 + h] = g1;
    pd[2 * 64 + h] = g2; pd[3 * 64 + h] = g3;
    pd[4 * 64 + h] = g4; pd[5 * 64 + h] = g5;
    pd[6 * 64 + h] = g6; pd[7 * 64 + h] = g7;
  }
}

// ---------------- fallback: fully fused, zero workspace (unused when ws ok) --
__global__ __launch_bounds__(64, 1) void seq_fused(
    const float* __restrict__ runs, const float* __restrict__ comm_init,
    const float* __restrict__ w1, const float* __restrict__ b1,
    const float* __restrict__ w2, const float* __restrict__ b2,
    const float* __restrict__ w3, const float* __restrict__ b3,
    float* __restrict__ out) {
  const int r = blockIdx.x;
  const int h = threadIdx.x;
  const int hb = h * 33;

  __shared__ float Asl[HID * 33];
  __shared__ float Bsl[HID * 33];
  __shared__ float commL[NA];
  __shared__ __align__(16) float h1s[HID];
  __shared__ float w1xs[XS * HID];
  __shared__ __align__(16) float xsl[96];

  for (int j = 0; j < 31; ++j) Asl[hb + j] = w1[h * DIN + 93 + j];
  Asl[hb + 31] = 0.f;
  Bsl[hb] = 0.f;
  for (int j = 1; j < 32; ++j) Bsl[hb + j] = w1[h * DIN + 92 + j];
  for (int k = 0; k < XS; ++k) w1xs[k * HID + h] = w1[h * DIN + k];

  float w2r[HID];
#pragma unroll
  for (int k = 0; k < HID; ++k) w2r[k] = w2[h * HID + k];
  const float b1h = b1[h];
  const float b2h = b2[h];
  const float w30h = w3[h], w31h = w3[HID + h], w32h = w3[2 * HID + h];
  const float b30 = b3[0], b31 = b3[1], b32 = b3[2];
  if (h < NA) commL[h] = comm_init[r * NA + h];

  const float* xbase = runs + (size_t)r * STEPS_PER_RUN * XS;
  float xa = xbase[h];
  float xb = (h < XS - 64) ? xbase[64 + h] : 0.f;
  float* outp = out + (size_t)r * STEPS_PER_RUN * 2;
  __syncthreads();

  int s = 0;
  for (int t = 0; t < T_STEPS; ++t) {
    float FB = 0.f;
#pragma unroll
    for (int j = 0; j < NA; ++j) FB = fmaf(Bsl[hb + j], commL[j], FB);
    float Q = 0.f, S = 0.f;
    for (int i = 0; i < NA; ++i, ++s) {
      int sn = s + 1; if (sn > STEPS_PER_RUN - 1) sn = STEPS_PER_RUN - 1;
      const float* xn = xbase + (size_t)sn * XS;
      xsl[h] = xa;
      if (h < XS - 64) xsl[64 + h] = xb;
      __syncthreads();
      float xa_n = xn[h];
      float xb_n = (h < XS - 64) ? xn[64 + h] : 0.f;
      float a0 = b1h, a1 = 0.f, a2 = 0.f;
#pragma unroll 4
      for (int k = 0; k < 31; ++k) {
        a0 = fmaf(xsl[3 * k],     w1xs[(3 * k) * HID + h],     a0);
        a1 = fmaf(xsl[3 * k + 1], w1xs[(3 * k + 1) * HID + h], a1);
        a2 = fmaf(xsl[3 * k + 2], w1xs[(3 * k + 2) * HID + h], a2);
      }
      float old_i = commL[i];
      S = fmaf(Bsl[hb + i], old_i, S);
      float h1 = fast_tanh(((a0 + a1) + a2) + FB + Q - S);
      h1s[h] = h1;
      __syncthreads();
      float c0 = b2h, c1 = 0.f, c2 = 0.f, c3 = 0.f;
      const float4* hv4 = (const float4*)h1s;
#pragma unroll
      for (int k4 = 0; k4 < 16; ++k4) {
        float4 hv = hv4[k4];
        c0 = fmaf(w2r[4 * k4 + 0], hv.x, c0);
        c1 = fmaf(w2r[4 * k4 + 1], hv.y, c1);
        c2 = fmaf(w2r[4 * k4 + 2], hv.z, c2);
        c3 = fmaf(w2r[4 * k4 + 3], hv.w, c3);
      }
      float h2 = fast_tanh((c0 + c1) + (c2 + c3));
      float o0 = wave64_sum_bcast(w30h * h2) + b30;
      float o1 = wave64_sum_bcast(w31h * h2) + b31;
      float c_new = wave64_sum_bcast(w32h * h2) + b32;
      if (h == 0) *(float2*)(outp + (size_t)s * 2) = make_float2(o0, o1);
      Q = fmaf(Asl[hb + i], c_new, Q);
      if (h == i) commL[h] = c_new;
      __syncthreads();
      xa = xa_n; xb = xb_n;
    }
  }
}

extern "C" void kernel_launch(void* const* d_in, const int* in_sizes, int n_in,
                              void* d_out, int out_size, void* d_ws, size_t ws_size,
                              hipStream_t stream) {
  const float* runs = (const float*)d_in[0];
  const float* comm_init = (const float*)d_in[1];
  const float* w1 = (const float*)d_in[2];
  const float* b1 = (const float*)d_in[3];
  const float* w2 = (const float*)d_in[4];
  const float* b2 = (const float*)d_in[5];
  const float* w3 = (const float*)d_in[6];
  const float* b3 = (const float*)d_in[7];
  float* out = (float*)d_out;

  if (ws_size >= WS_NEEDED) {
    float* w1T4 = (float*)d_ws;
    float* pre1 = (float*)((char*)d_ws + PRE1_OFF);
    hipLaunchKernelGGL(transpose_w1, dim3((24 * HID * 4 + 255) / 256), dim3(256), 0, stream,
                       w1, w1T4);
    hipLaunchKernelGGL(pre1_kernel, dim3(RTI_TOT / (PRE1_BATCH * 4)), dim3(256), 0, stream,
                       runs, w1T4, b1, pre1);
    hipLaunchKernelGGL(seq_kernel, dim3(R_RUNS), dim3(64), 0, stream,
                       w1, w2, b2, w3, b3, comm_init, pre1);
    hipLaunchKernelGGL(out_kernel, dim3(RTI_TOT / 256), dim3(256), 0, stream,
                       pre1, w3, b3, out);
  } else {
    hipLaunchKernelGGL(seq_fused, dim3(R_RUNS), dim3(64), 0, stream,
                       runs, comm_init, w1, b1, w2, b2, w3, b3, out);
  }
}

// Round 8
// 3836.704 us; speedup vs baseline: 2.0377x; 1.1262x over previous
//
#include <hip/hip_runtime.h>

// ---------------------------------------------------------------------------
// ComNet: R=16 runs x T=512 steps x 32 agents, sequential agent scan.
//   k0: repack W1[:, :93] -> w1T4 [24][64][4] (k padded to 96 with zeros)
//   k1: pre1[rti][h] = SC*(b1[h] + xs(93) . W1xs)  (reg-blocked, 4 rti/wave)
//   k2: wave-synchronous sequential kernel, 16 blocks x 1 wave.
//   k3: out_kernel: o0/o1 = w3[0:2] . h2 (h2 spilled by k2), parallel.
// R10: exp2-folded activations, butterfly csum, h2 spill: 5049->3819us seq.
// R11: split-K W2 dot (4 b128) + pre1 reg-block: NULL (3785us seq) ->
//   broadcast READ ISSUE not critical; round-trip LATENCY is. total-seq gap
//   (~530us) invariant to pre1 rework -> launch/other overhead, not pre1.
// R14: issue+chain diet at 1-wave serialization:
//   (a) A2/B2 columns in REGISTERS (time-invariant; loaded once; full i
//       unroll keeps indices static) -> no Asl/Bsl LDS, -2 ds_read/step;
//       FB refresh from B2r regs + commL reads.
//   (b) broadcast r1 = rcp(exp2(E)+1) instead of h1=1-2r1; fold -2 into the
//       f16 W2 weights, add SC*rowsum(w2 row) to the f32 base -> one fewer
//       dependent op before the LDS round trip.
//   (c) full unroll of i (32) for cross-step scheduling freedom.
// ---------------------------------------------------------------------------

#define R_RUNS 16
#define T_STEPS 512
#define NA 32
#define HID 64
#define XS 93                       // (NA-1)*3
#define DIN 124
#define STEPS_PER_RUN (T_STEPS * NA)        // 16384
#define RTI_TOT (R_RUNS * STEPS_PER_RUN)    // 262144

#define PRE1_OFF 65536
#define WS_NEEDED ((size_t)PRE1_OFF + (size_t)RTI_TOT * HID * 4 + 4096)

typedef _Float16 half2_t __attribute__((ext_vector_type(2)));
typedef unsigned int uint2v __attribute__((ext_vector_type(2)));

#if defined(__has_builtin)
#if __has_builtin(__builtin_amdgcn_permlane16_swap) && __has_builtin(__builtin_amdgcn_permlane32_swap)
#define HAVE_PLSWAP 1
#endif
#endif
#ifndef HAVE_PLSWAP
#define HAVE_PLSWAP 0
#endif

#if defined(__has_builtin)
#if __has_builtin(__builtin_amdgcn_exp2f)
#define EXPFN(x) __builtin_amdgcn_exp2f(x)
#define SC 2.8853900817779268f      // 2*log2(e): exp(2x) = exp2(SC*x)
#define HAVE_EXP2 1
#endif
#endif
#ifndef HAVE_EXP2
#define EXPFN(x) __expf(x)          // fallback: exp(2x) with SC=2
#define SC 2.0f
#define HAVE_EXP2 0
#endif

__device__ __forceinline__ float fast_tanh(float x) {
  float e = __expf(2.f * x);
  return fmaf(-2.f, __builtin_amdgcn_rcpf(e + 1.f), 1.f);
}

__device__ __forceinline__ float dot2h(half2_t a, half2_t b, float c) {
#if __has_builtin(__builtin_amdgcn_fdot2)
  return __builtin_amdgcn_fdot2(a, b, c, false);
#else
  return fmaf((float)a.x, (float)b.x, fmaf((float)a.y, (float)b.y, c));
#endif
}

__device__ __forceinline__ half2_t bch(unsigned u) {
  return __builtin_bit_cast(half2_t, u);
}

#define DPP_ADD(x, ctrl, rmask) \
  (x) += __int_as_float(__builtin_amdgcn_update_dpp(0, __float_as_int(x), (ctrl), (rmask), 0xf, true))

// legacy shr-tree reduce (used by seq_fused)
__device__ __forceinline__ float wave64_sum_bcast(float x) {
  DPP_ADD(x, 0x111, 0xf);
  DPP_ADD(x, 0x112, 0xf);
  DPP_ADD(x, 0x114, 0xf);
  DPP_ADD(x, 0x118, 0xf);
  DPP_ADD(x, 0x142, 0xa);
  DPP_ADD(x, 0x143, 0xc);
  return __int_as_float(__builtin_amdgcn_readlane(__float_as_int(x), 63));
}

// all-lanes butterfly sum: DPP xor 1,2 + half/row mirror + permlane swaps.
__device__ __forceinline__ float wave64_sum_all(float x) {
  DPP_ADD(x, 0xB1, 0xf);    // quad_perm [1,0,3,2]  : ^1
  DPP_ADD(x, 0x4E, 0xf);    // quad_perm [2,3,0,1]  : ^2
  DPP_ADD(x, 0x141, 0xf);   // row_half_mirror
  DPP_ADD(x, 0x140, 0xf);   // row_mirror
#if HAVE_PLSWAP
  uint2v p = __builtin_amdgcn_permlane16_swap(__float_as_uint(x), __float_as_uint(x), false, false);
  x = __uint_as_float(p[0]) + __uint_as_float(p[1]);
  p = __builtin_amdgcn_permlane32_swap(__float_as_uint(x), __float_as_uint(x), false, false);
  x = __uint_as_float(p[0]) + __uint_as_float(p[1]);
  return x;
#else
  DPP_ADD(x, 0x142, 0xa);
  DPP_ADD(x, 0x143, 0xc);
  return __int_as_float(__builtin_amdgcn_readlane(__float_as_int(x), 63));
#endif
}

// ---------------- k0: repack W1 xs-part -> [24][64][4], zero-padded --------
__global__ void transpose_w1(const float* __restrict__ w1, float* __restrict__ w1T4) {
  int idx = blockIdx.x * blockDim.x + threadIdx.x;  // (kk*64+h)*4+c
  if (idx < 24 * HID * 4) {
    int c = idx & 3, h = (idx >> 2) & 63, kk = idx >> 8;
    int k = 4 * kk + c;
    w1T4[idx] = (k < XS) ? w1[h * DIN + k] : 0.f;
  }
}

// ---------------- k1: pre1 = SC * (b1 + xs @ W1xs^T), reg-blocked ----------
#define PRE1_BATCH 4
__global__ __launch_bounds__(256) void pre1_kernel(
    const float* __restrict__ runs, const float* __restrict__ w1T4,
    const float* __restrict__ b1, float* __restrict__ pre1) {
  const int wid = (blockIdx.x * 256 + threadIdx.x) >> 6;
  const int lane = threadIdx.x & 63;
  const int rti0 = wid * PRE1_BATCH;
  const float4* wv = (const float4*)w1T4;
  float4 w[24];
#pragma unroll
  for (int kk = 0; kk < 24; ++kk) w[kk] = wv[kk * 64 + lane];
  const float b1s = b1[lane];
#pragma unroll
  for (int u = 0; u < PRE1_BATCH; ++u) {
    const float* xs = runs + (size_t)(rti0 + u) * XS;
    float a0 = b1s, a1 = 0.f, a2 = 0.f, a3 = 0.f;
#pragma unroll
    for (int kk = 0; kk < 23; ++kk) {
      a0 = fmaf(xs[4 * kk + 0], w[kk].x, a0);
      a1 = fmaf(xs[4 * kk + 1], w[kk].y, a1);
      a2 = fmaf(xs[4 * kk + 2], w[kk].z, a2);
      a3 = fmaf(xs[4 * kk + 3], w[kk].w, a3);
    }
    a0 = fmaf(xs[92], w[23].x, a0);
    pre1[(size_t)(rti0 + u) * HID + lane] = SC * ((a0 + a1) + (a2 + a3));
  }
}

// ---------------- k3: o0/o1 from spilled h2 ----------------
__global__ __launch_bounds__(256) void out_kernel(
    const float* __restrict__ h2, const float* __restrict__ w3,
    const float* __restrict__ b3, float* __restrict__ out) {
  const int rti = blockIdx.x * 256 + threadIdx.x;
  const float4* hv4 = (const float4*)(h2 + (size_t)rti * HID);
  const float4* w0v = (const float4*)w3;
  const float4* w1v = (const float4*)(w3 + HID);
  float p00 = 0.f, p01 = 0.f, p02 = 0.f, p03 = 0.f;
  float p10 = 0.f, p11 = 0.f, p12 = 0.f, p13 = 0.f;
#pragma unroll
  for (int k = 0; k < 16; ++k) {
    float4 hv = hv4[k];
    float4 w0 = w0v[k];
    float4 w1r = w1v[k];
    p00 = fmaf(w0.x, hv.x, p00);  p01 = fmaf(w0.y, hv.y, p01);
    p02 = fmaf(w0.z, hv.z, p02);  p03 = fmaf(w0.w, hv.w, p03);
    p10 = fmaf(w1r.x, hv.x, p10); p11 = fmaf(w1r.y, hv.y, p11);
    p12 = fmaf(w1r.z, hv.z, p12); p13 = fmaf(w1r.w, hv.w, p13);
  }
  float o0 = ((p00 + p01) + (p02 + p03)) + b3[0];
  float o1 = ((p10 + p11) + (p12 + p13)) + b3[1];
  *(float2*)(out + (size_t)rti * 2) = make_float2(o0, o1);
}

// ---------------- k2: sequential core (wave-synchronous) ----------------
// A2r[j] = SC*w1[h][93+j] (j<=30, pad 0..32), B2r[j] = SC*w1[h][92+j]
// (j>=1, pad at 0 and 32) -- REGISTERS, time-invariant, static-indexed via
// full unroll. Broadcast quantity is r1 = rcp(exp2(E)+1); h1 = 1-2r1 folded
// into f16 weights (-2*SC*w2) + f32 base (b2s + SC*rowsum(w2 row)).
// pre1h2 is NOT restrict: consumed pre1 rows are reused as the h2 spill.
__global__ __launch_bounds__(64, 1) void seq_kernel(
    const float* __restrict__ w1, const float* __restrict__ w2,
    const float* __restrict__ b2, const float* __restrict__ w3,
    const float* __restrict__ b3, const float* __restrict__ comm_init,
    float* pre1h2) {
  const int h = threadIdx.x;
  const int r = blockIdx.x;

  __shared__ __align__(16) float commL[NA];
  __shared__ __align__(16) _Float16 h1s16[HID];   // broadcasts r1 (f16)
  __shared__ __align__(16) float pbuf[2][2048 + 64];  // t-row ring + pad slot

  // ---- A2/B2 columns in registers (time-invariant) ----
  float A2r[33], B2r[33];
#pragma unroll
  for (int j = 0; j < 31; ++j) A2r[j] = SC * w1[h * DIN + 93 + j];
  A2r[31] = 0.f;
  A2r[32] = 0.f;
  B2r[0] = 0.f;
#pragma unroll
  for (int j = 1; j < 32; ++j) B2r[j] = SC * w1[h * DIN + 92 + j];
  B2r[32] = 0.f;

  // ---- full own-row sum for the r-folding base ----
  const float* wOwn = w2 + h * HID;
  float rsum = 0.f;
#pragma unroll
  for (int k = 0; k < HID; ++k) rsum += wOwn[k];

#if HAVE_PLSWAP
  // split-K weights, folded by -2*SC: rows h and h^32, cols [hi*32, +32)
  const int hi = h >> 5;
  const float4* wA = (const float4*)(w2 + h * HID + hi * 32);
  const float4* wB = (const float4*)(w2 + (h ^ 32) * HID + hi * 32);
  const float4 A0 = wA[0], A1 = wA[1], A2v = wA[2], A3 = wA[3];
  const float4 A4 = wA[4], A5 = wA[5], A6 = wA[6], A7 = wA[7];
  const float4 B0 = wB[0], B1 = wB[1], B2v = wB[2], B3 = wB[3];
  const float4 B4 = wB[4], B5 = wB[5], B6 = wB[6], B7 = wB[7];
#define PK2N(n, f4) \
  const half2_t n##a = {(_Float16)(-2.f * SC * (f4).x), (_Float16)(-2.f * SC * (f4).y)}; \
  const half2_t n##b = {(_Float16)(-2.f * SC * (f4).z), (_Float16)(-2.f * SC * (f4).w)}
  PK2N(pa0, A0); PK2N(pa1, A1); PK2N(pa2, A2v); PK2N(pa3, A3);
  PK2N(pa4, A4); PK2N(pa5, A5); PK2N(pa6, A6);  PK2N(pa7, A7);
  PK2N(pb0, B0); PK2N(pb1, B1); PK2N(pb2, B2v); PK2N(pb3, B3);
  PK2N(pb4, B4); PK2N(pb5, B5); PK2N(pb6, B6);  PK2N(pb7, B7);
#undef PK2N
#else
  const float4* w2v = (const float4*)(w2 + h * HID);
  const float4 r0 = w2v[0],  r1q = w2v[1], r2q = w2v[2],  r3q = w2v[3];
  const float4 r4 = w2v[4],  r5 = w2v[5],  r6 = w2v[6],  r7 = w2v[7];
  const float4 r8 = w2v[8],  r9 = w2v[9],  r10 = w2v[10], r11 = w2v[11];
  const float4 r12 = w2v[12], r13 = w2v[13], r14 = w2v[14], r15 = w2v[15];
#define PK2N(n, f4) \
  const half2_t n##a = {(_Float16)(-2.f * SC * (f4).x), (_Float16)(-2.f * SC * (f4).y)}; \
  const half2_t n##b = {(_Float16)(-2.f * SC * (f4).z), (_Float16)(-2.f * SC * (f4).w)}
  PK2N(q0, r0);  PK2N(q1, r1q); PK2N(q2, r2q); PK2N(q3, r3q);
  PK2N(q4, r4);  PK2N(q5, r5);  PK2N(q6, r6);  PK2N(q7, r7);
  PK2N(q8, r8);  PK2N(q9, r9);  PK2N(q10, r10); PK2N(q11, r11);
  PK2N(q12, r12); PK2N(q13, r13); PK2N(q14, r14); PK2N(q15, r15);
#undef PK2N
#endif

  const float base2 = SC * b2[h] + SC * rsum;   // y2 = base2 + dots(r)
  const float w32h = w3[2 * HID + h];
  const float w32n2 = -2.f * w32h;
  const float b32 = b3[2];

  float commR = (h < NA) ? comm_init[r * NA + h] : 0.f;
  if (h < NA) commL[h] = commR;

  float* prow = pre1h2 + (size_t)r * STEPS_PER_RUN * HID;

  // prime rows 0 and 1 into the LDS ring
  {
    const float4* s0 = (const float4*)prow;
    const float4* s1 = (const float4*)(prow + 2048);
    float4* d0 = (float4*)&pbuf[0][0];
    float4* d1 = (float4*)&pbuf[1][0];
#pragma unroll
    for (int j = 0; j < 8; ++j) d0[j * 64 + h] = s0[j * 64 + h];
#pragma unroll
    for (int j = 0; j < 8; ++j) d1[j * 64 + h] = s1[j * 64 + h];
  }

  for (int t = 0; t < T_STEPS; ++t) {
    float* pb = pbuf[t & 1];
    int tk = (t + 2 <= T_STEPS - 1) ? t + 2 : T_STEPS - 1;
    const float4* gsrc = (const float4*)(prow + (size_t)tk * 2048);
    float4 g0 = gsrc[0 * 64 + h], g1 = gsrc[1 * 64 + h];
    float4 g2 = gsrc[2 * 64 + h], g3 = gsrc[3 * 64 + h];
    float4 g4 = gsrc[4 * 64 + h], g5 = gsrc[5 * 64 + h];
    float4 g6 = gsrc[6 * 64 + h], g7 = gsrc[7 * 64 + h];

    // FB2 refresh from B2r registers + commL (8 b128 reads, amortized /32)
    const float4* cv4 = (const float4*)commL;
    float f0 = 0.f, f1 = 0.f, f2 = 0.f, f3 = 0.f;
#pragma unroll
    for (int q = 0; q < 8; ++q) {
      float4 c = cv4[q];
      f0 = fmaf(B2r[4 * q + 0], c.x, f0);
      f1 = fmaf(B2r[4 * q + 1], c.y, f1);
      f2 = fmaf(B2r[4 * q + 2], c.z, f2);
      f3 = fmaf(B2r[4 * q + 3], c.w, f3);
    }
    const float FB2 = (f0 + f1) + (f2 + f3);
    const float c0s = commR;
    float Q2 = 0.f, S2 = 0.f;
    float E = pb[h] + FB2;             // step-0 pre-act (B2r[0]=0, Q=0)
    float* h2t = prow + (size_t)t * 2048;

#pragma unroll
    for (int i = 0; i < NA; ++i) {
      float pf2_n = pb[(i + 1) * 64 + h];
      float old_n = __int_as_float(__builtin_amdgcn_readlane(__float_as_int(c0s), i + 1));
      // ---- on-chain: r1 from carried E (no 1-2r fma before broadcast) ----
      float e1 = EXPFN(E);
      float r1v = __builtin_amdgcn_rcpf(e1 + 1.f);
      h1s16[h] = (_Float16)r1v;
      // ---- off-chain during the LDS round trip ----
      float S2n = fmaf(B2r[i + 1], old_n, S2);
      float Qb2 = fmaf(A2r[i], b32, Q2);
      float H = pf2_n + (FB2 - S2n) + Qb2;
      float y2;
#if HAVE_PLSWAP
      const uint4* hv = (const uint4*)h1s16;
      uint4 X0 = hv[hi * 4 + 0], X1 = hv[hi * 4 + 1];
      uint4 X2 = hv[hi * 4 + 2], X3 = hv[hi * 4 + 3];
      float a0 = base2, a1 = 0.f, a2 = 0.f, a3 = 0.f;
#define DOTP(Xq, e, o) \
      a0 = dot2h(pa##e##a, bch(Xq.x), a0); a2 = dot2h(pb##e##a, bch(Xq.x), a2); \
      a1 = dot2h(pa##e##b, bch(Xq.y), a1); a3 = dot2h(pb##e##b, bch(Xq.y), a3); \
      a0 = dot2h(pa##o##a, bch(Xq.z), a0); a2 = dot2h(pb##o##a, bch(Xq.z), a2); \
      a1 = dot2h(pa##o##b, bch(Xq.w), a1); a3 = dot2h(pb##o##b, bch(Xq.w), a3)
      DOTP(X0, 0, 1); DOTP(X1, 2, 3); DOTP(X2, 4, 5); DOTP(X3, 6, 7);
#undef DOTP
      float pA = a0 + a1;                       // own-row partial (+base2)
      float pBo = a2 + a3;                      // partner-row partial
      uint2v sw = __builtin_amdgcn_permlane32_swap(
          __float_as_uint(pBo), __float_as_uint(pBo), false, false);
      float pB = hi ? __uint_as_float(sw[0]) : __uint_as_float(sw[1]);
      y2 = pA + pB;
#else
      const uint4* hv = (const uint4*)h1s16;
      uint4 X0 = hv[0], X1 = hv[1], X2 = hv[2], X3 = hv[3];
      uint4 X4 = hv[4], X5 = hv[5], X6 = hv[6], X7 = hv[7];
      float a0 = base2, a1 = 0.f, a2 = 0.f, a3 = 0.f;
#define DOTB(Xq, qe, qo) \
      a0 = dot2h(qe##a, bch(Xq.x), a0); a1 = dot2h(qe##b, bch(Xq.y), a1); \
      a2 = dot2h(qo##a, bch(Xq.z), a2); a3 = dot2h(qo##b, bch(Xq.w), a3)
      DOTB(X0, q0, q1);   DOTB(X1, q2, q3);
      DOTB(X2, q4, q5);   DOTB(X3, q6, q7);
      DOTB(X4, q8, q9);   DOTB(X5, q10, q11);
      DOTB(X6, q12, q13); DOTB(X7, q14, q15);
#undef DOTB
      y2 = (a0 + a1) + (a2 + a3);
#endif
      float e2 = EXPFN(y2);
      float r2v = __builtin_amdgcn_rcpf(e2 + 1.f);
      float xr = fmaf(w32n2, r2v, w32h);        // = w32h * h2
      float csum = wave64_sum_all(xr);
      // ---- off-chain epilogue ----
      float h2v = fmaf(-2.f, r2v, 1.f);
      h2t[i * 64 + h] = h2v;
      float c_new = csum + b32;
      commR = (h == i) ? c_new : commR;
      E = fmaf(A2r[i], csum, H);
      Q2 = fmaf(A2r[i], csum, Qb2);
      S2 = S2n;
    }
    if (h < NA) commL[h] = commR;
    float4* pd = (float4*)pb;
    pd[0 * 64 + h] = g0; pd[1 * 64 + h] = g1;
    pd[2 * 64 + h] = g2; pd[3 * 64 + h] = g3;
    pd[4 * 64 + h] = g4; pd[5 * 64 + h] = g5;
    pd[6 * 64 + h] = g6; pd[7 * 64 + h] = g7;
  }
}

// ---------------- fallback: fully fused, zero workspace (unused when ws ok) --
__global__ __launch_bounds__(64, 1) void seq_fused(
    const float* __restrict__ runs, const float* __restrict__ comm_init,
    const float* __restrict__ w1, const float* __restrict__ b1,
    const float* __restrict__ w2, const float* __restrict__ b2,
    const float* __restrict__ w3, const float* __restrict__ b3,
    float* __restrict__ out) {
  const int r = blockIdx.x;
  const int h = threadIdx.x;
  const int hb = h * 33;

  __shared__ float Asl[HID * 33];
  __shared__ float Bsl[HID * 33];
  __shared__ float commL[NA];
  __shared__ __align__(16) float h1s[HID];
  __shared__ float w1xs[XS * HID];
  __shared__ __align__(16) float xsl[96];

  for (int j = 0; j < 31; ++j) Asl[hb + j] = w1[h * DIN + 93 + j];
  Asl[hb + 31] = 0.f;
  Bsl[hb] = 0.f;
  for (int j = 1; j < 32; ++j) Bsl[hb + j] = w1[h * DIN + 92 + j];
  for (int k = 0; k < XS; ++k) w1xs[k * HID + h] = w1[h * DIN + k];

  float w2r[HID];
#pragma unroll
  for (int k = 0; k < HID; ++k) w2r[k] = w2[h * HID + k];
  const float b1h = b1[h];
  const float b2h = b2[h];
  const float w30h = w3[h], w31h = w3[HID + h], w32h = w3[2 * HID + h];
  const float b30 = b3[0], b31 = b3[1], b32 = b3[2];
  if (h < NA) commL[h] = comm_init[r * NA + h];

  const float* xbase = runs + (size_t)r * STEPS_PER_RUN * XS;
  float xa = xbase[h];
  float xb = (h < XS - 64) ? xbase[64 + h] : 0.f;
  float* outp = out + (size_t)r * STEPS_PER_RUN * 2;
  __syncthreads();

  int s = 0;
  for (int t = 0; t < T_STEPS; ++t) {
    float FB = 0.f;
#pragma unroll
    for (int j = 0; j < NA; ++j) FB = fmaf(Bsl[hb + j], commL[j], FB);
    float Q = 0.f, S = 0.f;
    for (int i = 0; i < NA; ++i, ++s) {
      int sn = s + 1; if (sn > STEPS_PER_RUN - 1) sn = STEPS_PER_RUN - 1;
      const float* xn = xbase + (size_t)sn * XS;
      xsl[h] = xa;
      if (h < XS - 64) xsl[64 + h] = xb;
      __syncthreads();
      float xa_n = xn[h];
      float xb_n = (h < XS - 64) ? xn[64 + h] : 0.f;
      float a0 = b1h, a1 = 0.f, a2 = 0.f;
#pragma unroll 4
      for (int k = 0; k < 31; ++k) {
        a0 = fmaf(xsl[3 * k],     w1xs[(3 * k) * HID + h],     a0);
        a1 = fmaf(xsl[3 * k + 1], w1xs[(3 * k + 1) * HID + h], a1);
        a2 = fmaf(xsl[3 * k + 2], w1xs[(3 * k + 2) * HID + h], a2);
      }
      float old_i = commL[i];
      S = fmaf(Bsl[hb + i], old_i, S);
      float h1 = fast_tanh(((a0 + a1) + a2) + FB + Q - S);
      h1s[h] = h1;
      __syncthreads();
      float c0 = b2h, c1 = 0.f, c2 = 0.f, c3 = 0.f;
      const float4* hv4 = (const float4*)h1s;
#pragma unroll
      for (int k4 = 0; k4 < 16; ++k4) {
        float4 hv = hv4[k4];
        c0 = fmaf(w2r[4 * k4 + 0], hv.x, c0);
        c1 = fmaf(w2r[4 * k4 + 1], hv.y, c1);
        c2 = fmaf(w2r[4 * k4 + 2], hv.z, c2);
        c3 = fmaf(w2r[4 * k4 + 3], hv.w, c3);
      }
      float h2 = fast_tanh((c0 + c1) + (c2 + c3));
      float o0 = wave64_sum_bcast(w30h * h2) + b30;
      float o1 = wave64_sum_bcast(w31h * h2) + b31;
      float c_new = wave64_sum_bcast(w32h * h2) + b32;
      if (h == 0) *(float2*)(outp + (size_t)s * 2) = make_float2(o0, o1);
      Q = fmaf(Asl[hb + i], c_new, Q);
      if (h == i) commL[h] = c_new;
      __syncthreads();
      xa = xa_n; xb = xb_n;
    }
  }
}

extern "C" void kernel_launch(void* const* d_in, const int* in_sizes, int n_in,
                              void* d_out, int out_size, void* d_ws, size_t ws_size,
                              hipStream_t stream) {
  const float* runs = (const float*)d_in[0];
  const float* comm_init = (const float*)d_in[1];
  const float* w1 = (const float*)d_in[2];
  const float* b1 = (const float*)d_in[3];
  const float* w2 = (const float*)d_in[4];
  const float* b2 = (const float*)d_in[5];
  const float* w3 = (const float*)d_in[6];
  const float* b3 = (const float*)d_in[7];
  float* out = (float*)d_out;

  if (ws_size >= WS_NEEDED) {
    float* w1T4 = (float*)d_ws;
    float* pre1 = (float*)((char*)d_ws + PRE1_OFF);
    hipLaunchKernelGGL(transpose_w1, dim3((24 * HID * 4 + 255) / 256), dim3(256), 0, stream,
                       w1, w1T4);
    hipLaunchKernelGGL(pre1_kernel, dim3(RTI_TOT / (PRE1_BATCH * 4)), dim3(256), 0, stream,
                       runs, w1T4, b1, pre1);
    hipLaunchKernelGGL(seq_kernel, dim3(R_RUNS), dim3(64), 0, stream,
                       w1, w2, b2, w3, b3, comm_init, pre1);
    hipLaunchKernelGGL(out_kernel, dim3(RTI_TOT / 256), dim3(256), 0, stream,
                       pre1, w3, b3, out);
  } else {
    hipLaunchKernelGGL(seq_fused, dim3(R_RUNS), dim3(64), 0, stream,
                       runs, comm_init, w1, b1, w2, b2, w3, b3, out);
  }
}